// Round 5
// baseline (932.176 us; speedup 1.0000x reference)
//
#include <hip/hip_runtime.h>

#define NN 50000
#define NE 400000
#define D 128
#define KXP 288      // GEMM1 K padded (264 -> 288)
#define KXR 264
#define XSTR 296     // x-tile LDS stride (bf16 elems); 64*XSTR*2 = 37888 B
#define EPSV 1e-3f

typedef unsigned short u16;
typedef unsigned int u32;
typedef __attribute__((ext_vector_type(4))) float f32x4;
typedef __attribute__((ext_vector_type(4))) float float4v;
typedef __attribute__((ext_vector_type(8))) short short8;
typedef __attribute__((ext_vector_type(8))) unsigned short ushort8;
typedef __attribute__((ext_vector_type(4))) unsigned short ushort4v;

__device__ __forceinline__ u16 f2b(float f){
  u32 u = __float_as_uint(f);
  u32 r = u + 0x7fffu + ((u >> 16) & 1u);
  return (u16)(r >> 16);
}
__device__ __forceinline__ float b2f(u16 s){ return __uint_as_float(((u32)s) << 16); }
__device__ __forceinline__ float silu_f(float x){ return x / (1.f + expf(-x)); }
__device__ __forceinline__ void atomAddF(float* p, float v){ unsafeAtomicAdd(p, v); }

// ---------------- prep: h -> bf16 (vectorized) ----------------
__global__ void k_prep_h(const float* __restrict__ h, u16* __restrict__ hbf){
  int i = (blockIdx.x * 256 + threadIdx.x) * 4;
  if (i < NN * D){
    float4v v = *(const float4v*)(h + i);
    ushort4v o = { f2b(v[0]), f2b(v[1]), f2b(v[2]), f2b(v[3]) };
    *(ushort4v*)(hbf + i) = o;
  }
}

// ---------------- prep: transposed bf16 weights ----------------
__global__ void k_prep_w(const float* __restrict__ m_w1, const float* __restrict__ m_w2,
                         const float* __restrict__ c_w1, const float* __restrict__ het_w,
                         const float* __restrict__ c_w2,
                         u16* __restrict__ W1t, u16* __restrict__ W2t,
                         u16* __restrict__ C1t, u16* __restrict__ HtT,
                         u16* __restrict__ C2t){
  int i = blockIdx.x * 256 + threadIdx.x;
  if (i < D * KXP){
    int c = i / KXP, k = i - c * KXP;
    W1t[i] = f2b(k < KXR ? m_w1[k * D + c] : 0.f);
    return;
  }
  i -= D * KXP;
  if (i < D * D){ int c = i >> 7, k = i & 127; W2t[i] = f2b(m_w2[k * D + c]); return; }
  i -= D * D;
  if (i < D * D){ int c = i >> 7, k = i & 127; C1t[i] = f2b(c_w1[k * D + c]); return; }
  i -= D * D;
  if (i < D * D){ int c = i >> 7, k = i & 127; HtT[i] = f2b(het_w[k * D + c]); return; }
  i -= D * D;
  if (i < 16 * D){ int n = i >> 7, k = i & 127; C2t[i] = f2b(n < 8 ? c_w2[k * 8 + n] : 0.f); return; }
}

// ---------------- per-node: csum, pooled, ts ----------------
__global__ void k_node_pre(const float* __restrict__ coords, const float* __restrict__ cw,
                           float* __restrict__ pooled, int* __restrict__ tsn){
  int n = blockIdx.x * 256 + threadIdx.x;
  if (n >= NN) return;
  int cs = 0; float px = 0.f, py = 0.f, pz = 0.f;
  #pragma unroll
  for (int c = 0; c < 8; c++){
    float w = cw[n * 8 + c];
    if (w != 0.f){
      cs++;
      px += coords[(size_t)n * 24 + c * 3 + 0];
      py += coords[(size_t)n * 24 + c * 3 + 1];
      pz += coords[(size_t)n * 24 + c * 3 + 2];
    }
  }
  float inv = 1.f / ((float)cs + EPSV);
  pooled[n * 3 + 0] = px * inv;
  pooled[n * 3 + 1] = py * inv;
  pooled[n * 3 + 2] = pz * inv;
  int ts = cs - 1; ts = ts < 0 ? 0 : (ts > 7 ? 7 : ts);
  tsn[n] = ts;
}

// ---------------- edge pass A: global max sq-norm + in-degree ----------------
__global__ __launch_bounds__(256) void k_edge_max(const float* __restrict__ coords,
                                                  const int* __restrict__ el,
                                                  u32* __restrict__ maxsq, u32* __restrict__ cnt){
  int e = blockIdx.x * 256 + threadIdx.x;
  float vm = 0.f;
  if (e < NE){
    int s = el[e * 3 + 0], t = el[e * 3 + 1];
    float ct[24], cs_[24];
    #pragma unroll
    for (int i = 0; i < 24; i++) ct[i] = coords[(size_t)t * 24 + i];
    #pragma unroll
    for (int i = 0; i < 24; i++) cs_[i] = coords[(size_t)s * 24 + i];
    #pragma unroll
    for (int c1 = 0; c1 < 8; c1++){
      #pragma unroll
      for (int c2 = 0; c2 < 8; c2++){
        float dx = ct[c1 * 3 + 0] - cs_[c2 * 3 + 0];
        float dy = ct[c1 * 3 + 1] - cs_[c2 * 3 + 1];
        float dz = ct[c1 * 3 + 2] - cs_[c2 * 3 + 2];
        vm = fmaxf(vm, dx * dx + dy * dy + dz * dz);
      }
    }
    atomicAdd(&cnt[t], 1u);
  }
  __shared__ float red[256];
  red[threadIdx.x] = vm;
  __syncthreads();
  for (int s2 = 128; s2 > 0; s2 >>= 1){
    if (threadIdx.x < s2) red[threadIdx.x] = fmaxf(red[threadIdx.x], red[threadIdx.x + s2]);
    __syncthreads();
  }
  if (threadIdx.x == 0) atomicMax(maxsq, __float_as_uint(red[0]));
}

// ---------------- CSR scan: row_start = exclusive prefix of cnt ----------------
__global__ __launch_bounds__(1024) void k_scan(const u32* __restrict__ cnt,
                                               u32* __restrict__ row_start,
                                               u32* __restrict__ fill_ptr){
  __shared__ u32 s[1024];
  const int tid = threadIdx.x;
  const int base = tid * 49;
  u32 tot = 0;
  #pragma unroll 1
  for (int k = 0; k < 49; k++){
    int i = base + k;
    if (i < NN) tot += cnt[i];
  }
  s[tid] = tot;
  __syncthreads();
  for (int off = 1; off < 1024; off <<= 1){
    u32 v = (tid >= off) ? s[tid - off] : 0u;
    __syncthreads();
    s[tid] += v;
    __syncthreads();
  }
  u32 running = s[tid] - tot;   // exclusive prefix
  #pragma unroll 1
  for (int k = 0; k < 49; k++){
    int i = base + k;
    if (i <= NN){
      row_start[i] = running;
      if (i < NN){ fill_ptr[i] = running; running += cnt[i]; }
    }
  }
}

// ---------------- CSR fill: eidx sorted by tgt ----------------
__global__ __launch_bounds__(256) void k_fill(const int* __restrict__ el,
                                              u32* __restrict__ fill_ptr,
                                              int* __restrict__ eidx){
  int e = blockIdx.x * 256 + threadIdx.x;
  if (e >= NE) return;
  int t = el[e * 3 + 1];
  u32 pos = atomicAdd(&fill_ptr[t], 1u);
  eidx[pos] = e;
}

// ---------------- fused radial + edge MLP ----------------
// LDS x-tile region reuse (all wave-local rows; wave-lockstep keeps LDS order):
//   radial scratch (f32, per-wave quarter of sx): SA 16x65 + ST 16x65
//   __syncthreads
//   phase 0: cols 0..287 = x   (h[tgt] | h[src] | radial | 0-pad)
//   GEMM1 epilogue: cols 0..127  = m1
//   GEMM2 epilogue: cols 128..255 = m  (WS: store m bf16; else node atomics)
//   GEMM3 epilogue: cols 0..127  = ef1
template<bool WS>
__global__ __launch_bounds__(256, 2) void k_edge_mlp(
    const int* __restrict__ el, const float* __restrict__ ewg,
    const u16* __restrict__ hbf, const float* __restrict__ attr,
    const float* __restrict__ cw, const float* __restrict__ rl_w,
    const float* __restrict__ rl_b, const u32* __restrict__ maxsq,
    const u16* __restrict__ W1t, const u16* __restrict__ W2t, const u16* __restrict__ C1t,
    const u16* __restrict__ C2t,
    const float* __restrict__ m_b1, const float* __restrict__ m_b2,
    const float* __restrict__ c_b1,
    const int* __restrict__ tsn,
    const int* __restrict__ eidx,            // WS path
    u16* __restrict__ m_bf, float* __restrict__ pe8,
    int* __restrict__ src_s, float* __restrict__ ew_s,
    const float* __restrict__ coords,
    const float* __restrict__ pooled, const float* __restrict__ w_r,
    float* __restrict__ out_node, float* __restrict__ out_coord)
{
  __shared__ u16 sx[64 * XSTR];
  __shared__ float sef[64 * 8];
  __shared__ int s_tgt[64];
  __shared__ int s_src[64];
  __shared__ float s_ew[64];

  const int tid = threadIdx.x;
  const int lane = tid & 63;
  const int wv = tid >> 6;          // wave 0..3, owns rows [16*wv, 16*wv+16)
  const int wrow = wv * 16;
  const int e0 = blockIdx.x * 64;
  const int lc = lane & 15;
  const int lk = (lane >> 4) * 8;
  const f32x4 zero = {0.f, 0.f, 0.f, 0.f};

  // ================= RADIAL (fused) =================
  const int rl_ = lane >> 2;        // local edge row within wave
  const int q = lane & 3;           // quarter thread
  const int er = wrow + rl_;
  const int p = e0 + er;            // sorted position (WS) or edge id (atomic)
  const int e = WS ? eidx[p] : p;
  const int s = el[e * 3 + 0];
  const int t = el[e * 3 + 1];
  const float ew = ewg[e];
  if (q == 0){
    s_src[er] = s; s_tgt[er] = t; s_ew[er] = ew;
    if (WS){ src_s[p] = s; ew_s[p] = ew; }
  }

  float* fsc = (float*)sx;
  const int WQ = wv * 2368;                 // per-wave f32 quarter (16 x-rows = 2368 f32)
  #define SA(r, idx) fsc[WQ + (r) * 65 + (idx)]
  #define ST(r, idx) fsc[WQ + 1040 + (r) * 65 + (idx)]

  // stage As = attr[src] (8x8) into per-wave scratch
  #pragma unroll
  for (int i = 0; i < 16; i++) SA(rl_, q * 16 + i) = attr[(size_t)s * 64 + q * 16 + i];

  float ct6[6], cs24[24], cwt2[2], cws8[8];
  #pragma unroll
  for (int i = 0; i < 6; i++)  ct6[i]  = coords[(size_t)t * 24 + 6 * q + i];
  #pragma unroll
  for (int i = 0; i < 24; i++) cs24[i] = coords[(size_t)s * 24 + i];
  cwt2[0] = cw[(size_t)t * 8 + 2 * q + 0];
  cwt2[1] = cw[(size_t)t * 8 + 2 * q + 1];
  #pragma unroll
  for (int i = 0; i < 8; i++)  cws8[i] = cw[(size_t)s * 8 + i];

  const float scale = 1.f / (sqrtf(__uint_as_float(*maxsq)) + EPSV);

  // tmp[ci][b] = sum_d msg[2q+ci][d] * As[d][b]
  float tmp[2][8];
  #pragma unroll
  for (int ci = 0; ci < 2; ci++)
    #pragma unroll
    for (int b = 0; b < 8; b++) tmp[ci][b] = 0.f;
  #pragma unroll
  for (int d = 0; d < 8; d++){
    float asd[8];
    #pragma unroll
    for (int b = 0; b < 8; b++) asd[b] = SA(rl_, d * 8 + b);
    #pragma unroll
    for (int ci = 0; ci < 2; ci++){
      float dx = ct6[ci * 3 + 0] - cs24[d * 3 + 0];
      float dy = ct6[ci * 3 + 1] - cs24[d * 3 + 1];
      float dz = ct6[ci * 3 + 2] - cs24[d * 3 + 2];
      float msg = sqrtf(dx * dx + dy * dy + dz * dz) * scale * cwt2[ci] * cws8[d];
      #pragma unroll
      for (int b = 0; b < 8; b++) tmp[ci][b] += msg * asd[b];
    }
  }
  #pragma unroll
  for (int ci = 0; ci < 2; ci++)
    #pragma unroll
    for (int b = 0; b < 8; b++) ST(rl_, (2 * q + ci) * 8 + b) = tmp[ci][b];

  // rad[ai][b] = sum_c At[c][2q+ai] * tmp[c][b]
  float rad[2][8];
  #pragma unroll
  for (int ai = 0; ai < 2; ai++)
    #pragma unroll
    for (int b = 0; b < 8; b++) rad[ai][b] = 0.f;
  #pragma unroll
  for (int c = 0; c < 8; c++){
    float at0 = attr[(size_t)t * 64 + c * 8 + 2 * q + 0];
    float at1 = attr[(size_t)t * 64 + c * 8 + 2 * q + 1];
    #pragma unroll
    for (int b = 0; b < 8; b++){
      float tv = ST(rl_, c * 8 + b);
      rad[0][b] += at0 * tv;
      rad[1][b] += at1 * tv;
    }
  }
  float sq = 0.f;
  #pragma unroll
  for (int ai = 0; ai < 2; ai++)
    #pragma unroll
    for (int b = 0; b < 8; b++) sq += rad[ai][b] * rad[ai][b];
  sq += __shfl_xor(sq, 1);
  sq += __shfl_xor(sq, 2);
  const float rn = 1.f / (sqrtf(sq) + EPSV);

  float o[8];
  #pragma unroll
  for (int j = 0; j < 8; j++) o[j] = 0.f;
  #pragma unroll
  for (int ai = 0; ai < 2; ai++){
    #pragma unroll
    for (int b = 0; b < 8; b++){
      float v = rad[ai][b] * rn;
      int row = (2 * q + ai) * 8 + b;
      #pragma unroll
      for (int j = 0; j < 8; j++) o[j] += v * rl_w[row * 8 + j];
    }
  }
  #pragma unroll
  for (int j = 0; j < 8; j++){
    o[j] += __shfl_xor(o[j], 1);
    o[j] += __shfl_xor(o[j], 2);
  }

  __syncthreads();   // radial scratch (f32) -> x-tile (u16) handoff

  // ================= x-tile staging =================
  {
    const u16* srow = (q < 2) ? (hbf + (size_t)t * D + q * 64)
                              : (hbf + (size_t)s * D + (q - 2) * 64);
    const int colbase = (q < 2) ? (q * 64) : (128 + (q - 2) * 64);
    u16* dst = sx + er * XSTR + colbase;
    #pragma unroll
    for (int i = 0; i < 8; i++)
      *(ushort8*)(dst + i * 8) = *(const ushort8*)(srow + i * 8);
    if (q == 0){
      #pragma unroll
      for (int j = 0; j < 8; j++) sx[er * XSTR + 256 + j] = f2b(o[j] + rl_b[j]);
      #pragma unroll
      for (int j = 264; j < 288; j++) sx[er * XSTR + j] = 0;
    }
  }
  // no barrier: GEMM rows are wave-local from here on

  f32x4 acc[8];

  // ---- GEMM1: m1 = silu(x @ W1 + b1) -> cols 0..127 ----
  #pragma unroll
  for (int nb = 0; nb < 8; nb++) acc[nb] = zero;
  #pragma unroll
  for (int kb = 0; kb < 9; kb++){
    short8 a = *(const short8*)(sx + (wrow + lc) * XSTR + kb * 32 + lk);
    #pragma unroll
    for (int nb = 0; nb < 8; nb++){
      short8 b = *(const short8*)(W1t + (size_t)(nb * 16 + lc) * KXP + kb * 32 + lk);
      acc[nb] = __builtin_amdgcn_mfma_f32_16x16x32_bf16(a, b, acc[nb], 0, 0, 0);
    }
  }
  #pragma unroll
  for (int nb = 0; nb < 8; nb++){
    const int col = nb * 16 + lc;
    const float bias = m_b1[col];
    #pragma unroll
    for (int j = 0; j < 4; j++){
      const int row = wrow + (lane >> 4) * 4 + j;
      sx[row * XSTR + col] = f2b(silu_f(acc[nb][j] + bias));
    }
  }

  // ---- GEMM2: m = silu(m1 @ W2 + b2) -> cols 128..255 ----
  #pragma unroll
  for (int nb = 0; nb < 8; nb++) acc[nb] = zero;
  #pragma unroll
  for (int kb = 0; kb < 4; kb++){
    short8 a = *(const short8*)(sx + (wrow + lc) * XSTR + kb * 32 + lk);
    #pragma unroll
    for (int nb = 0; nb < 8; nb++){
      short8 b = *(const short8*)(W2t + (size_t)(nb * 16 + lc) * D + kb * 32 + lk);
      acc[nb] = __builtin_amdgcn_mfma_f32_16x16x32_bf16(a, b, acc[nb], 0, 0, 0);
    }
  }
  #pragma unroll
  for (int nb = 0; nb < 8; nb++){
    const int col = nb * 16 + lc;
    const float bias = m_b2[col];
    #pragma unroll
    for (int j = 0; j < 4; j++){
      const int row = wrow + (lane >> 4) * 4 + j;
      const float v = silu_f(acc[nb][j] + bias);
      const u16 vb = f2b(v);
      if (WS){
        m_bf[(size_t)(e0 + row) * D + col] = vb;           // store raw m (bf16)
      } else {
        atomAddF(&out_node[(size_t)s_tgt[row] * D + col], v * s_ew[row]);
      }
      sx[row * XSTR + 128 + col] = vb;
    }
  }

  // ---- GEMM3: ef1 = silu(m @ c_w1 + c_b1) -> cols 0..127 ----
  #pragma unroll
  for (int nb = 0; nb < 8; nb++) acc[nb] = zero;
  #pragma unroll
  for (int kb = 0; kb < 4; kb++){
    short8 a = *(const short8*)(sx + (wrow + lc) * XSTR + 128 + kb * 32 + lk);
    #pragma unroll
    for (int nb = 0; nb < 8; nb++){
      short8 b = *(const short8*)(C1t + (size_t)(nb * 16 + lc) * D + kb * 32 + lk);
      acc[nb] = __builtin_amdgcn_mfma_f32_16x16x32_bf16(a, b, acc[nb], 0, 0, 0);
    }
  }
  #pragma unroll
  for (int nb = 0; nb < 8; nb++){
    const int col = nb * 16 + lc;
    const float bias = c_b1[col];
    #pragma unroll
    for (int j = 0; j < 4; j++){
      const int row = wrow + (lane >> 4) * 4 + j;
      sx[row * XSTR + col] = f2b(silu_f(acc[nb][j] + bias));
    }
  }

  // ---- GEMM4 (MFMA): edge_feat = ef1 @ c_w2 (8 real cols, padded to 16) ----
  {
    f32x4 a4 = zero;
    #pragma unroll
    for (int kb = 0; kb < 4; kb++){
      short8 a = *(const short8*)(sx + (wrow + lc) * XSTR + kb * 32 + lk);
      short8 b = *(const short8*)(C2t + (size_t)lc * D + kb * 32 + lk);
      a4 = __builtin_amdgcn_mfma_f32_16x16x32_bf16(a, b, a4, 0, 0, 0);
    }
    if (lc < 8){
      #pragma unroll
      for (int j = 0; j < 4; j++){
        const int row = wrow + (lane >> 4) * 4 + j;
        sef[row * 8 + lc] = a4[j];
      }
    }
  }

  // ---- pooled_edge (+ coord scatter in atomic path) ----
  {
    const int ts = tsn[t];
    const int w8 = 8 - ts;
    const float invw = 1.f / (float)w8;
    if (WS){
      #pragma unroll
      for (int ci = 0; ci < 2; ci++){
        const int c = q * 2 + ci;
        float pe = 0.f;
        const int hi = (c + w8 < 8) ? (c + w8) : 8;
        for (int j = c; j < hi; j++) pe += sef[er * 8 + j];
        pe8[(size_t)p * 8 + c] = pe * invw;
      }
    } else {
      const float wr0 = w_r[0];
      const float p0 = pooled[s * 3 + 0], p1 = pooled[s * 3 + 1], p2 = pooled[s * 3 + 2];
      #pragma unroll
      for (int ci = 0; ci < 2; ci++){
        const int c = q * 2 + ci;
        float pe = 0.f;
        const int hi = (c + w8 < 8) ? (c + w8) : 8;
        for (int j = c; j < hi; j++) pe += sef[er * 8 + j];
        pe *= invw * wr0;
        const size_t ob = (size_t)t * 24 + c * 3;
        atomAddF(&out_coord[ob + 0], (coords[(size_t)t * 24 + c * 3 + 0] - p0) * pe);
        atomAddF(&out_coord[ob + 1], (coords[(size_t)t * 24 + c * 3 + 1] - p1) * pe);
        atomAddF(&out_coord[ob + 2], (coords[(size_t)t * 24 + c * 3 + 2] - p2) * pe);
      }
    }
  }
  #undef SA
  #undef ST
}

// ---------------- gather: node_agg (bf16) + coord output ----------------
__global__ __launch_bounds__(256) void k_agg(
    const u32* __restrict__ row_start, const u16* __restrict__ m_bf,
    const float* __restrict__ ew_s, const float* __restrict__ pe8,
    const int* __restrict__ src_s, const float* __restrict__ pooled,
    const float* __restrict__ coords, const float* __restrict__ w_r,
    u16* __restrict__ nagg, float* __restrict__ out_coord)
{
  const int lane = threadIdx.x & 63;
  const int wv = threadIdx.x >> 6;
  const int n = blockIdx.x * 4 + wv;
  if (n >= NN) return;
  const u32 r0 = row_start[n], r1 = row_start[n + 1];
  const int cA = lane / 3, dA = lane - cA * 3;   // lanes 0..23 -> (c,d)
  float acc0 = 0.f, acc1 = 0.f;   // cols lane*2, lane*2+1
  float sp = 0.f;                  // lanes 0..7: sum pe[c]
  float sqd = 0.f;                 // lanes 0..23: sum pooled[src][d]*pe[c]
  for (u32 p = r0; p < r1; p++){
    u32 mv = *(const u32*)(m_bf + (size_t)p * D + lane * 2);
    float ew = ew_s[p];
    acc0 += b2f((u16)(mv & 0xffffu)) * ew;
    acc1 += b2f((u16)(mv >> 16)) * ew;
    if (lane < 8)  sp  += pe8[(size_t)p * 8 + lane];
    if (lane < 24) sqd += pooled[(size_t)src_s[p] * 3 + dA] * pe8[(size_t)p * 8 + cA];
  }
  u32 pk = (u32)f2b(acc0) | ((u32)f2b(acc1) << 16);
  *(u32*)(nagg + (size_t)n * D + lane * 2) = pk;
  if (lane < 24){
    const float wr0 = w_r[0];
    const float spc = __shfl(sp, cA);
    const float cv = coords[(size_t)n * 24 + lane];
    const u32 deg = r1 - r0;
    const float dv = (float)(deg > 0u ? deg : 1u);
    out_coord[(size_t)n * 24 + lane] = cv + wr0 * (cv * spc - sqd) / dv;
  }
}

// ---------------- final A: het GEMM + BN + silu + residual ----------------
#define MSTR 136
__global__ __launch_bounds__(256) void k_finalA(
    const float* __restrict__ h, const u16* __restrict__ nagg,
    const u16* __restrict__ HtT, const float* __restrict__ het_b,
    const float* __restrict__ bn_g, const float* __restrict__ bn_b,
    float* __restrict__ out_node)
{
  __shared__ u16 sa[64 * MSTR];
  const int tid = threadIdx.x, lane = tid & 63, wv = tid >> 6, wrow = wv * 16;
  const int nb0 = blockIdx.x * 64;
  const int lc = lane & 15, lk = (lane >> 4) * 8;
  const f32x4 zero = {0.f, 0.f, 0.f, 0.f};

  // stage nagg rows (wave-local, vectorized)
  #pragma unroll
  for (int jj = 0; jj < 4; jj++){
    const int flat = jj * 64 + lane;
    const int r = wrow + (flat >> 4);
    const int c8 = flat & 15;
    int rn = nb0 + r; if (rn >= NN) rn = NN - 1;
    *(ushort8*)(sa + r * MSTR + c8 * 8) = *(const ushort8*)(nagg + (size_t)rn * D + c8 * 8);
  }

  f32x4 acc[8];
  #pragma unroll
  for (int nb = 0; nb < 8; nb++) acc[nb] = zero;
  #pragma unroll
  for (int kb = 0; kb < 4; kb++){
    short8 a = *(const short8*)(sa + (wrow + lc) * MSTR + kb * 32 + lk);
    #pragma unroll
    for (int nb = 0; nb < 8; nb++){
      short8 b = *(const short8*)(HtT + (size_t)(nb * 16 + lc) * D + kb * 32 + lk);
      acc[nb] = __builtin_amdgcn_mfma_f32_16x16x32_bf16(a, b, acc[nb], 0, 0, 0);
    }
  }
  const float invs = rsqrtf(1.f + 1e-5f);
  #pragma unroll
  for (int nb = 0; nb < 8; nb++){
    const int col = nb * 16 + lc;
    const float hb = het_b[col], g = bn_g[col], be = bn_b[col];
    #pragma unroll
    for (int j = 0; j < 4; j++){
      const int row = wrow + (lane >> 4) * 4 + j;
      const int node = nb0 + row;
      if (node < NN){
        float v = silu_f((acc[nb][j] + hb) * invs * g + be);
        out_node[(size_t)node * D + col] = v + h[(size_t)node * D + col];
      }
    }
  }
}

// ---------------- final B (atomic path): het GEMM + coord finalize ----------------
__global__ __launch_bounds__(256) void k_finalB(
    const float* __restrict__ h, const float* __restrict__ coords,
    const u16* __restrict__ HtT, const float* __restrict__ het_b,
    const float* __restrict__ bn_g, const float* __restrict__ bn_b,
    const u32* __restrict__ cnt, float* __restrict__ dout)
{
  __shared__ u16 sa[64 * MSTR];
  const int tid = threadIdx.x, lane = tid & 63, wv = tid >> 6, wrow = wv * 16;
  const int nb0 = blockIdx.x * 64;
  float* out_node = dout;
  float* out_coord = dout + (size_t)NN * D;
  const int lc = lane & 15, lk = (lane >> 4) * 8;
  const f32x4 zero = {0.f, 0.f, 0.f, 0.f};

  #pragma unroll
  for (int i = 0; i < 32; i++){
    const int idx = i * 64 + lane;
    const int r = idx >> 7, c = idx & 127;
    int rn = nb0 + wrow + r; if (rn >= NN) rn = NN - 1;
    sa[(wrow + r) * MSTR + c] = f2b(out_node[(size_t)rn * D + c]);
  }

  f32x4 acc[8];
  #pragma unroll
  for (int nb = 0; nb < 8; nb++) acc[nb] = zero;
  #pragma unroll
  for (int kb = 0; kb < 4; kb++){
    short8 a = *(const short8*)(sa + (wrow + lc) * MSTR + kb * 32 + lk);
    #pragma unroll
    for (int nb = 0; nb < 8; nb++){
      short8 b = *(const short8*)(HtT + (size_t)(nb * 16 + lc) * D + kb * 32 + lk);
      acc[nb] = __builtin_amdgcn_mfma_f32_16x16x32_bf16(a, b, acc[nb], 0, 0, 0);
    }
  }
  const float invs = rsqrtf(1.f + 1e-5f);
  #pragma unroll
  for (int nb = 0; nb < 8; nb++){
    const int col = nb * 16 + lc;
    const float hb = het_b[col], g = bn_g[col], be = bn_b[col];
    #pragma unroll
    for (int j = 0; j < 4; j++){
      const int row = wrow + (lane >> 4) * 4 + j;
      const int node = nb0 + row;
      if (node < NN){
        float v = silu_f((acc[nb][j] + hb) * invs * g + be);
        out_node[(size_t)node * D + col] = v + h[(size_t)node * D + col];
      }
    }
  }
  #pragma unroll
  for (int i = 0; i < 6; i++){
    const int idx = i * 256 + tid;
    const int nl = idx / 24, rem = idx - nl * 24;
    const int node = nb0 + nl;
    if (node < NN){
      const size_t o = (size_t)node * 24 + rem;
      const u32 cn = cnt[node];
      const float cv = (float)(cn > 0u ? cn : 1u);
      out_coord[o] = coords[o] + out_coord[o] / cv;
    }
  }
}

extern "C" void kernel_launch(void* const* d_in, const int* in_sizes, int n_in,
                              void* d_out, int out_size, void* d_ws, size_t ws_size,
                              hipStream_t stream)
{
  const float* h      = (const float*)d_in[0];
  const float* coords = (const float*)d_in[1];
  const float* cattr  = (const float*)d_in[2];
  const float* cw     = (const float*)d_in[3];
  const float* ewg    = (const float*)d_in[4];
  const int*   el     = (const int*)  d_in[5];
  const float* rl_w   = (const float*)d_in[6];
  const float* rl_b   = (const float*)d_in[7];
  const float* m_w1   = (const float*)d_in[8];
  const float* m_b1   = (const float*)d_in[9];
  const float* m_w2   = (const float*)d_in[10];
  const float* m_b2   = (const float*)d_in[11];
  const float* c_w1   = (const float*)d_in[12];
  const float* c_b1   = (const float*)d_in[13];
  const float* c_w2   = (const float*)d_in[14];
  const float* het_w  = (const float*)d_in[15];
  const float* het_b  = (const float*)d_in[16];
  const float* bn_g   = (const float*)d_in[17];
  const float* bn_b   = (const float*)d_in[18];
  const float* w_r    = (const float*)d_in[19];

  char* wsb = (char*)d_ws;
  size_t off = 0;
  auto take = [&](size_t bytes)->char*{
    char* p = wsb + off;
    off = (off + bytes + 255) & ~(size_t)255;
    return p;
  };
  // common
  u32*   maxsq  = (u32*)  take(4);
  float* pooled = (float*)take((size_t)NN * 3 * 4);
  int*   tsn    = (int*)  take((size_t)NN * 4);
  u32*   cnt    = (u32*)  take((size_t)NN * 4);
  u16*   hbf    = (u16*)  take((size_t)NN * D * 2);
  u16*   W1t    = (u16*)  take((size_t)D * KXP * 2);
  u16*   W2t    = (u16*)  take((size_t)D * D * 2);
  u16*   C1t    = (u16*)  take((size_t)D * D * 2);
  u16*   HtT    = (u16*)  take((size_t)D * D * 2);
  u16*   C2t    = (u16*)  take((size_t)16 * D * 2);
  // CSR-gather path extras
  u32*   row_start = (u32*)  take((size_t)(NN + 1) * 4);
  u32*   fill_ptr  = (u32*)  take((size_t)NN * 4);
  int*   eidx      = (int*)  take((size_t)NE * 4);
  int*   src_s     = (int*)  take((size_t)NE * 4);
  float* ew_s      = (float*)take((size_t)NE * 4);
  float* pe8       = (float*)take((size_t)NE * 8 * 4);
  u16*   nagg      = (u16*)  take((size_t)NN * D * 2);
  u16*   m_bf      = (u16*)  take((size_t)NE * D * 2);
  const bool useA = (off <= ws_size);

  float* out_node  = (float*)d_out;
  float* out_coord = out_node + (size_t)NN * D;

  (void)hipMemsetAsync(maxsq, 0, 4, stream);
  (void)hipMemsetAsync(cnt, 0, (size_t)NN * 4, stream);

  k_prep_h  <<<dim3((NN * D / 4 + 255) / 256), dim3(256), 0, stream>>>(h, hbf);
  k_prep_w  <<<dim3((D * KXP + 3 * D * D + 16 * D) / 256), dim3(256), 0, stream>>>(
        m_w1, m_w2, c_w1, het_w, c_w2, W1t, W2t, C1t, HtT, C2t);
  k_node_pre<<<dim3((NN + 255) / 256), dim3(256), 0, stream>>>(coords, cw, pooled, tsn);
  k_edge_max<<<dim3((NE + 255) / 256), dim3(256), 0, stream>>>(coords, el, maxsq, cnt);

  if (useA){
    k_scan<<<dim3(1), dim3(1024), 0, stream>>>(cnt, row_start, fill_ptr);
    k_fill<<<dim3((NE + 255) / 256), dim3(256), 0, stream>>>(el, fill_ptr, eidx);
    k_edge_mlp<true><<<dim3(NE / 64), dim3(256), 0, stream>>>(
        el, ewg, hbf, cattr, cw, rl_w, rl_b, maxsq,
        W1t, W2t, C1t, C2t, m_b1, m_b2, c_b1, tsn,
        eidx, m_bf, pe8, src_s, ew_s,
        coords, pooled, w_r, out_node, out_coord);
    k_agg<<<dim3((NN + 3) / 4), dim3(256), 0, stream>>>(
        row_start, m_bf, ew_s, pe8, src_s, pooled, coords, w_r, nagg, out_coord);
    k_finalA<<<dim3((NN + 63) / 64), dim3(256), 0, stream>>>(
        h, nagg, HtT, het_b, bn_g, bn_b, out_node);
  } else {
    (void)hipMemsetAsync(d_out, 0, (size_t)out_size * sizeof(float), stream);
    k_edge_mlp<false><<<dim3(NE / 64), dim3(256), 0, stream>>>(
        el, ewg, hbf, cattr, cw, rl_w, rl_b, maxsq,
        W1t, W2t, C1t, C2t, m_b1, m_b2, c_b1, tsn,
        eidx, m_bf, pe8, src_s, ew_s,
        coords, pooled, w_r, out_node, out_coord);
    k_finalB<<<dim3((NN + 63) / 64), dim3(256), 0, stream>>>(
        h, coords, HtT, het_b, bn_g, bn_b, cnt, (float*)d_out);
  }
}

// Round 6
// 783.973 us; speedup vs baseline: 1.1890x; 1.1890x over previous
//
#include <hip/hip_runtime.h>

#define NN 50000
#define NE 400000
#define D 128
#define MST 136
#define EPSV 1e-3f

typedef unsigned short u16;
typedef unsigned int u32;
typedef __attribute__((ext_vector_type(4))) float f32x4;
typedef __attribute__((ext_vector_type(4))) float float4v;
typedef __attribute__((ext_vector_type(8))) short short8;
typedef __attribute__((ext_vector_type(8))) unsigned short ushort8;
typedef __attribute__((ext_vector_type(4))) unsigned short ushort4v;

__device__ __forceinline__ u16 f2b(float f){
  u32 u = __float_as_uint(f);
  u32 r = u + 0x7fffu + ((u >> 16) & 1u);
  return (u16)(r >> 16);
}
__device__ __forceinline__ float b2f(u16 s){ return __uint_as_float(((u32)s) << 16); }
__device__ __forceinline__ float silu_f(float x){
  return x * __builtin_amdgcn_rcpf(1.f + __expf(-x));
}
__device__ __forceinline__ void atomAddF(float* p, float v){ unsafeAtomicAdd(p, v); }

// ---------------- prep: h -> bf16 ----------------
__global__ void k_prep_h(const float* __restrict__ h, u16* __restrict__ hbf){
  int i = (blockIdx.x * 256 + threadIdx.x) * 4;
  if (i < NN * D){
    float4v v = *(const float4v*)(h + i);
    ushort4v o = { f2b(v[0]), f2b(v[1]), f2b(v[2]), f2b(v[3]) };
    *(ushort4v*)(hbf + i) = o;
  }
}

// ---------------- prep: transposed bf16 weights ----------------
// W12t[256][128]: col<128 -> W1[k][col] (h_t half), col>=128 -> W1[128+k][col-128] (h_s half)
// W1cT[128][32]: j<8 -> W1[256+j][c]; j==8 -> b1[c] (constant-1 trick); else 0
__global__ void k_prep_w(const float* __restrict__ m_w1, const float* __restrict__ m_b1,
                         const float* __restrict__ m_w2, const float* __restrict__ c_w1,
                         const float* __restrict__ c_w2, const float* __restrict__ het_w,
                         u16* __restrict__ W12t, u16* __restrict__ W1cT,
                         u16* __restrict__ W2t, u16* __restrict__ C1t,
                         u16* __restrict__ HtT, u16* __restrict__ C2t){
  int i = blockIdx.x * 256 + threadIdx.x;
  if (i < 256 * 128){
    int c = i >> 7, k = i & 127;
    W12t[i] = f2b(c < 128 ? m_w1[k * D + c] : m_w1[(128 + k) * D + (c - 128)]);
    return;
  }
  i -= 256 * 128;
  if (i < 128 * 32){
    int c = i >> 5, j = i & 31;
    W1cT[i] = (j < 8) ? f2b(m_w1[(256 + j) * D + c]) : (j == 8 ? f2b(m_b1[c]) : (u16)0);
    return;
  }
  i -= 128 * 32;
  if (i < D * D){ int c = i >> 7, k = i & 127; W2t[i] = f2b(m_w2[k * D + c]); return; }
  i -= D * D;
  if (i < D * D){ int c = i >> 7, k = i & 127; C1t[i] = f2b(c_w1[k * D + c]); return; }
  i -= D * D;
  if (i < D * D){ int c = i >> 7, k = i & 127; HtT[i] = f2b(het_w[k * D + c]); return; }
  i -= D * D;
  if (i < 16 * D){ int n = i >> 7, k = i & 127; C2t[i] = f2b(n < 8 ? c_w2[k * 8 + n] : 0.f); return; }
}

// ---------------- per-node: pooled, ts ----------------
__global__ void k_node_pre(const float* __restrict__ coords, const float* __restrict__ cw,
                           float* __restrict__ pooled, int* __restrict__ tsn){
  int n = blockIdx.x * 256 + threadIdx.x;
  if (n >= NN) return;
  int cs = 0; float px = 0.f, py = 0.f, pz = 0.f;
  #pragma unroll
  for (int c = 0; c < 8; c++){
    float w = cw[n * 8 + c];
    if (w != 0.f){
      cs++;
      px += coords[(size_t)n * 24 + c * 3 + 0];
      py += coords[(size_t)n * 24 + c * 3 + 1];
      pz += coords[(size_t)n * 24 + c * 3 + 2];
    }
  }
  float inv = 1.f / ((float)cs + EPSV);
  pooled[n * 3 + 0] = px * inv;
  pooled[n * 3 + 1] = py * inv;
  pooled[n * 3 + 2] = pz * inv;
  int ts = cs - 1; ts = ts < 0 ? 0 : (ts > 7 ? 7 : ts);
  tsn[n] = ts;
}

// ---------------- edge pass A: global max sq-norm + in-degree ----------------
__global__ __launch_bounds__(256) void k_edge_max(const float* __restrict__ coords,
                                                  const int* __restrict__ el,
                                                  u32* __restrict__ maxsq, u32* __restrict__ cnt){
  int e = blockIdx.x * 256 + threadIdx.x;
  float vm = 0.f;
  if (e < NE){
    int s = el[e * 3 + 0], t = el[e * 3 + 1];
    float ct[24], cs_[24];
    const float4v* pt = (const float4v*)(coords + (size_t)t * 24);
    const float4v* ps = (const float4v*)(coords + (size_t)s * 24);
    #pragma unroll
    for (int i = 0; i < 6; i++){
      float4v v = pt[i];
      ct[i*4] = v[0]; ct[i*4+1] = v[1]; ct[i*4+2] = v[2]; ct[i*4+3] = v[3];
    }
    #pragma unroll
    for (int i = 0; i < 6; i++){
      float4v v = ps[i];
      cs_[i*4] = v[0]; cs_[i*4+1] = v[1]; cs_[i*4+2] = v[2]; cs_[i*4+3] = v[3];
    }
    #pragma unroll
    for (int c1 = 0; c1 < 8; c1++){
      #pragma unroll
      for (int c2 = 0; c2 < 8; c2++){
        float dx = ct[c1*3+0] - cs_[c2*3+0];
        float dy = ct[c1*3+1] - cs_[c2*3+1];
        float dz = ct[c1*3+2] - cs_[c2*3+2];
        vm = fmaxf(vm, dx*dx + dy*dy + dz*dz);
      }
    }
    atomicAdd(&cnt[t], 1u);
  }
  __shared__ float red[256];
  red[threadIdx.x] = vm;
  __syncthreads();
  for (int s2 = 128; s2 > 0; s2 >>= 1){
    if (threadIdx.x < s2) red[threadIdx.x] = fmaxf(red[threadIdx.x], red[threadIdx.x + s2]);
    __syncthreads();
  }
  if (threadIdx.x == 0) atomicMax(maxsq, __float_as_uint(red[0]));
}

// ---------------- CSR scan ----------------
__global__ __launch_bounds__(1024) void k_scan(const u32* __restrict__ cnt,
                                               u32* __restrict__ row_start,
                                               u32* __restrict__ fill_ptr){
  __shared__ u32 s[1024];
  const int tid = threadIdx.x;
  const int base = tid * 49;
  u32 tot = 0;
  #pragma unroll 1
  for (int k = 0; k < 49; k++){
    int i = base + k;
    if (i < NN) tot += cnt[i];
  }
  s[tid] = tot;
  __syncthreads();
  for (int off = 1; off < 1024; off <<= 1){
    u32 v = (tid >= off) ? s[tid - off] : 0u;
    __syncthreads();
    s[tid] += v;
    __syncthreads();
  }
  u32 running = s[tid] - tot;
  #pragma unroll 1
  for (int k = 0; k < 49; k++){
    int i = base + k;
    if (i <= NN){
      row_start[i] = running;
      if (i < NN){ fill_ptr[i] = running; running += cnt[i]; }
    }
  }
}

// ---------------- CSR fill ----------------
__global__ __launch_bounds__(256) void k_fill(const int* __restrict__ el,
                                              u32* __restrict__ fill_ptr,
                                              int* __restrict__ eidx){
  int e = blockIdx.x * 256 + threadIdx.x;
  if (e >= NE) return;
  int t = el[e * 3 + 1];
  u32 pos = atomicAdd(&fill_ptr[t], 1u);
  eidx[pos] = e;
}

// ---------------- radial (sorted order), writes rad8b/st_s/ew_s ----------------
__global__ __launch_bounds__(256) void k_radial(const float* __restrict__ coords,
                                                const float* __restrict__ attr,
                                                const float* __restrict__ cw,
                                                const int* __restrict__ el,
                                                const int* __restrict__ eidx,
                                                const float* __restrict__ ewg,
                                                const float* __restrict__ rl_w,
                                                const float* __restrict__ rl_b,
                                                const u32* __restrict__ maxsq,
                                                u16* __restrict__ rad8b,
                                                u32* __restrict__ st_s,
                                                float* __restrict__ ew_s){
  __shared__ float sct[64][24], scs[64][24], sAs[64][64], scwt[64][8], scws[64][8], stmp[64][64];
  const int tid = threadIdx.x;
  const int er = tid >> 2;
  const int q = tid & 3;
  const int p = blockIdx.x * 64 + er;
  const int e = eidx[p];
  const int s = el[e * 3 + 0];
  const int t = el[e * 3 + 1];
  if (q == 0){
    st_s[p] = ((u32)t << 16) | (u32)s;
    ew_s[p] = ewg[e];
  }

  #pragma unroll
  for (int i = 0; i < 6; i++) sct[er][q * 6 + i] = coords[(size_t)t * 24 + q * 6 + i];
  #pragma unroll
  for (int i = 0; i < 6; i++) scs[er][q * 6 + i] = coords[(size_t)s * 24 + q * 6 + i];
  #pragma unroll
  for (int i = 0; i < 16; i++) sAs[er][q * 16 + i] = attr[(size_t)s * 64 + q * 16 + i];
  #pragma unroll
  for (int i = 0; i < 2; i++){
    scwt[er][q * 2 + i] = cw[(size_t)t * 8 + q * 2 + i];
    scws[er][q * 2 + i] = cw[(size_t)s * 8 + q * 2 + i];
  }
  __syncthreads();

  const float scale = 1.f / (sqrtf(__uint_as_float(*maxsq)) + EPSV);

  float tmp[2][8];
  #pragma unroll
  for (int ci = 0; ci < 2; ci++)
    #pragma unroll
    for (int b = 0; b < 8; b++) tmp[ci][b] = 0.f;
  #pragma unroll
  for (int d = 0; d < 8; d++){
    float asd[8];
    #pragma unroll
    for (int b = 0; b < 8; b++) asd[b] = sAs[er][d * 8 + b];
    #pragma unroll
    for (int ci = 0; ci < 2; ci++){
      int c = q * 2 + ci;
      float dx = sct[er][c * 3 + 0] - scs[er][d * 3 + 0];
      float dy = sct[er][c * 3 + 1] - scs[er][d * 3 + 1];
      float dz = sct[er][c * 3 + 2] - scs[er][d * 3 + 2];
      float msg = sqrtf(dx * dx + dy * dy + dz * dz) * scale * scwt[er][c] * scws[er][d];
      #pragma unroll
      for (int b = 0; b < 8; b++) tmp[ci][b] += msg * asd[b];
    }
  }
  #pragma unroll
  for (int ci = 0; ci < 2; ci++)
    #pragma unroll
    for (int b = 0; b < 8; b++) stmp[er][(q * 2 + ci) * 8 + b] = tmp[ci][b];
  __syncthreads();

  float rad[2][8];
  #pragma unroll
  for (int ai = 0; ai < 2; ai++)
    #pragma unroll
    for (int b = 0; b < 8; b++) rad[ai][b] = 0.f;
  #pragma unroll
  for (int c = 0; c < 8; c++){
    float at0 = attr[(size_t)t * 64 + c * 8 + 2 * q + 0];
    float at1 = attr[(size_t)t * 64 + c * 8 + 2 * q + 1];
    #pragma unroll
    for (int b = 0; b < 8; b++){
      float tv = stmp[er][c * 8 + b];
      rad[0][b] += at0 * tv;
      rad[1][b] += at1 * tv;
    }
  }
  float sq = 0.f;
  #pragma unroll
  for (int ai = 0; ai < 2; ai++)
    #pragma unroll
    for (int b = 0; b < 8; b++) sq += rad[ai][b] * rad[ai][b];
  sq += __shfl_xor(sq, 1);
  sq += __shfl_xor(sq, 2);
  const float rn = 1.f / (sqrtf(sq) + EPSV);

  float o[8];
  #pragma unroll
  for (int j = 0; j < 8; j++) o[j] = 0.f;
  #pragma unroll
  for (int ai = 0; ai < 2; ai++){
    #pragma unroll
    for (int b = 0; b < 8; b++){
      float v = rad[ai][b] * rn;
      int row = (2 * q + ai) * 8 + b;
      #pragma unroll
      for (int j = 0; j < 8; j++) o[j] += v * rl_w[row * 8 + j];
    }
  }
  #pragma unroll
  for (int j = 0; j < 8; j++){
    o[j] += __shfl_xor(o[j], 1);
    o[j] += __shfl_xor(o[j], 2);
  }
  if (q == 0){
    ushort8 o8;
    #pragma unroll
    for (int j = 0; j < 8; j++) o8[j] = f2b(o[j] + rl_b[j]);
    *(ushort8*)(rad8b + (size_t)p * 8) = o8;
  }
}

// ---------------- per-node precompute: hW12 = hbf @ [W1a|W1b] (f32 out) ----------------
__global__ __launch_bounds__(256) void k_hw12(const u16* __restrict__ hbf,
                                              const u16* __restrict__ W12t,
                                              float* __restrict__ hW12){
  __shared__ u16 sa[64 * MST];
  const int tid = threadIdx.x, lane = tid & 63, wv = tid >> 6, wrow = wv * 16;
  const int nb0 = blockIdx.x * 64;
  const int lc = lane & 15, lk = (lane >> 4) * 8;
  const f32x4 zero = {0.f, 0.f, 0.f, 0.f};

  #pragma unroll
  for (int jj = 0; jj < 4; jj++){
    const int flat = jj * 64 + lane;
    const int r = wrow + (flat >> 4);
    const int c8 = flat & 15;
    int rn = nb0 + r; if (rn >= NN) rn = NN - 1;
    *(ushort8*)(sa + r * MST + c8 * 8) = *(const ushort8*)(hbf + (size_t)rn * D + c8 * 8);
  }

  f32x4 acc[16];
  #pragma unroll
  for (int nb = 0; nb < 16; nb++) acc[nb] = zero;
  #pragma unroll
  for (int kb = 0; kb < 4; kb++){
    short8 a = *(const short8*)(sa + (wrow + lc) * MST + kb * 32 + lk);
    #pragma unroll
    for (int nb = 0; nb < 16; nb++){
      short8 b = *(const short8*)(W12t + (size_t)(nb * 16 + lc) * D + kb * 32 + lk);
      acc[nb] = __builtin_amdgcn_mfma_f32_16x16x32_bf16(a, b, acc[nb], 0, 0, 0);
    }
  }
  #pragma unroll
  for (int nb = 0; nb < 16; nb++){
    const int col = nb * 16 + lc;
    #pragma unroll
    for (int j = 0; j < 4; j++){
      const int row = wrow + (lane >> 4) * 4 + j;
      const int node = nb0 + row;
      if (node < NN) hW12[(size_t)node * 256 + col] = acc[nb][j];
    }
  }
}

// ---------------- fused edge MLP (sorted, CSR-segmented node_agg) ----------------
// 128 edges/block, 4 waves, 32 edges/wave (2 M-chunks of 16; B-frags reused 2x).
// LDS tile sm[128][MST] overlay: sum2(bf16) -> m1 -> m -> ef1 (all wave-local rows).
__global__ __launch_bounds__(256, 2) void k_edge_mlp(
    const u16* __restrict__ rad8b, const u32* __restrict__ st_s,
    const float* __restrict__ ew_s, const float* __restrict__ hW12,
    const u16* __restrict__ W1cT, const u16* __restrict__ W2t,
    const u16* __restrict__ C1t, const u16* __restrict__ C2t,
    const float* __restrict__ m_b2, const float* __restrict__ c_b1,
    const int* __restrict__ tsn,
    float* __restrict__ out_node, float* __restrict__ pe8)
{
  __shared__ u16 sm[128 * MST];
  __shared__ float sef[128 * 8];
  __shared__ int s_tgt[128];
  __shared__ float s_ew[128];

  const int tid = threadIdx.x;
  const int lane = tid & 63;
  const int wv = tid >> 6;
  const int wr = wv * 32;              // wave owns rows [wr, wr+32)
  const int e0 = blockIdx.x * 128;
  const int lc = lane & 15;
  const int khi = lane >> 4;
  const int lk = khi * 8;
  const f32x4 zero4 = {0.f, 0.f, 0.f, 0.f};
  const short8 zero8 = {0, 0, 0, 0, 0, 0, 0, 0};

  // stage tgt/ew for own rows (wave-local)
  if (lane < 32){
    u32 v = st_s[e0 + wr + lane];
    s_tgt[wr + lane] = (int)(v >> 16);
    s_ew[wr + lane] = ew_s[e0 + wr + lane];
  }

  // ---- stage-sum: sm[r][c] = bf16( hW12[t_r][c] + hW12[s_r][128+c] ) ----
  {
    const int r = wr + (lane >> 1);
    const int ch = (lane & 1) * 64;
    u32 v = st_s[e0 + r];
    const int t = (int)(v >> 16), s = (int)(v & 0xffffu);
    const float* pa = hW12 + (size_t)t * 256 + ch;
    const float* pb = hW12 + (size_t)s * 256 + 128 + ch;
    #pragma unroll
    for (int i = 0; i < 16; i++){
      float4v va = *(const float4v*)(pa + i * 4);
      float4v vb = *(const float4v*)(pb + i * 4);
      ushort4v o = { f2b(va[0] + vb[0]), f2b(va[1] + vb[1]),
                     f2b(va[2] + vb[2]), f2b(va[3] + vb[3]) };
      *(ushort4v*)(sm + r * MST + ch + i * 4) = o;
    }
  }

  f32x4 acc0[8], acc1[8];

  // ---- rproj: m1_pre = rad8 @ W1c + 1*b1 (single K-chunk MFMA) ----
  {
    short8 ar0, ar1;
    if (khi == 0){
      ar0 = *(const short8*)(rad8b + (size_t)(e0 + wr + lc) * 8);
      ar1 = *(const short8*)(rad8b + (size_t)(e0 + wr + 16 + lc) * 8);
    } else if (khi == 1){
      ar0 = zero8; ar0[0] = (short)0x3F80;  // bf16 1.0 at k=8 -> picks up b1 row
      ar1 = ar0;
    } else {
      ar0 = zero8; ar1 = zero8;
    }
    #pragma unroll
    for (int nb = 0; nb < 8; nb++){
      short8 b = *(const short8*)(W1cT + (size_t)(nb * 16 + lc) * 32 + lk);
      acc0[nb] = __builtin_amdgcn_mfma_f32_16x16x32_bf16(ar0, b, zero4, 0, 0, 0);
      acc1[nb] = __builtin_amdgcn_mfma_f32_16x16x32_bf16(ar1, b, zero4, 0, 0, 0);
    }
  }
  // epi1: m1 = silu(rproj + sum2) -> sm cols 0..127
  #pragma unroll
  for (int nb = 0; nb < 8; nb++){
    const int col = nb * 16 + lc;
    #pragma unroll
    for (int j = 0; j < 4; j++){
      const int r0 = wr + khi * 4 + j;
      const int r1 = r0 + 16;
      float v0 = silu_f(acc0[nb][j] + b2f(sm[r0 * MST + col]));
      float v1 = silu_f(acc1[nb][j] + b2f(sm[r1 * MST + col]));
      sm[r0 * MST + col] = f2b(v0);
      sm[r1 * MST + col] = f2b(v1);
    }
  }

  // ---- GEMM2: m = silu(m1 @ W2 + b2) -> sm cols 0..127 (overwrite) ----
  #pragma unroll
  for (int nb = 0; nb < 8; nb++){ acc0[nb] = zero4; acc1[nb] = zero4; }
  #pragma unroll
  for (int kb = 0; kb < 4; kb++){
    short8 a0 = *(const short8*)(sm + (wr + lc) * MST + kb * 32 + lk);
    short8 a1 = *(const short8*)(sm + (wr + 16 + lc) * MST + kb * 32 + lk);
    #pragma unroll
    for (int nb = 0; nb < 8; nb++){
      short8 b = *(const short8*)(W2t + (size_t)(nb * 16 + lc) * D + kb * 32 + lk);
      acc0[nb] = __builtin_amdgcn_mfma_f32_16x16x32_bf16(a0, b, acc0[nb], 0, 0, 0);
      acc1[nb] = __builtin_amdgcn_mfma_f32_16x16x32_bf16(a1, b, acc1[nb], 0, 0, 0);
    }
  }
  #pragma unroll
  for (int nb = 0; nb < 8; nb++){
    const int col = nb * 16 + lc;
    const float bias = m_b2[col];
    #pragma unroll
    for (int j = 0; j < 4; j++){
      const int r0 = wr + khi * 4 + j;
      const int r1 = r0 + 16;
      sm[r0 * MST + col] = f2b(silu_f(acc0[nb][j] + bias));
      sm[r1 * MST + col] = f2b(silu_f(acc1[nb][j] + bias));
    }
  }

  // ---- segmented node_agg reduction (cross-wave; edges sorted by tgt) ----
  __syncthreads();
  {
    const int c = tid & 127;
    const int half = tid >> 7;
    const int rb = half * 64;
    float accv = 0.f;
    int curt = s_tgt[rb];
    #pragma unroll 1
    for (int r = rb; r < rb + 64; r++){
      int tt = s_tgt[r];
      if (tt != curt){
        atomAddF(&out_node[(size_t)curt * D + c], accv);
        accv = 0.f; curt = tt;
      }
      accv += b2f(sm[r * MST + c]) * s_ew[r];
    }
    atomAddF(&out_node[(size_t)curt * D + c], accv);
  }
  __syncthreads();

  // ---- GEMM3: ef1 = silu(m @ c_w1 + c_b1) -> sm cols 0..127 (overwrite) ----
  #pragma unroll
  for (int nb = 0; nb < 8; nb++){ acc0[nb] = zero4; acc1[nb] = zero4; }
  #pragma unroll
  for (int kb = 0; kb < 4; kb++){
    short8 a0 = *(const short8*)(sm + (wr + lc) * MST + kb * 32 + lk);
    short8 a1 = *(const short8*)(sm + (wr + 16 + lc) * MST + kb * 32 + lk);
    #pragma unroll
    for (int nb = 0; nb < 8; nb++){
      short8 b = *(const short8*)(C1t + (size_t)(nb * 16 + lc) * D + kb * 32 + lk);
      acc0[nb] = __builtin_amdgcn_mfma_f32_16x16x32_bf16(a0, b, acc0[nb], 0, 0, 0);
      acc1[nb] = __builtin_amdgcn_mfma_f32_16x16x32_bf16(a1, b, acc1[nb], 0, 0, 0);
    }
  }
  #pragma unroll
  for (int nb = 0; nb < 8; nb++){
    const int col = nb * 16 + lc;
    const float bias = c_b1[col];
    #pragma unroll
    for (int j = 0; j < 4; j++){
      const int r0 = wr + khi * 4 + j;
      const int r1 = r0 + 16;
      sm[r0 * MST + col] = f2b(silu_f(acc0[nb][j] + bias));
      sm[r1 * MST + col] = f2b(silu_f(acc1[nb][j] + bias));
    }
  }

  // ---- GEMM4: ef = ef1 @ c_w2 (8 cols padded to 16) ----
  {
    f32x4 e40 = zero4, e41 = zero4;
    #pragma unroll
    for (int kb = 0; kb < 4; kb++){
      short8 a0 = *(const short8*)(sm + (wr + lc) * MST + kb * 32 + lk);
      short8 a1 = *(const short8*)(sm + (wr + 16 + lc) * MST + kb * 32 + lk);
      short8 b = *(const short8*)(C2t + (size_t)lc * D + kb * 32 + lk);
      e40 = __builtin_amdgcn_mfma_f32_16x16x32_bf16(a0, b, e40, 0, 0, 0);
      e41 = __builtin_amdgcn_mfma_f32_16x16x32_bf16(a1, b, e41, 0, 0, 0);
    }
    if (lc < 8){
      #pragma unroll
      for (int j = 0; j < 4; j++){
        sef[(wr + khi * 4 + j) * 8 + lc] = e40[j];
        sef[(wr + 16 + khi * 4 + j) * 8 + lc] = e41[j];
      }
    }
  }

  // ---- pooled_edge windows -> pe8 (wave-local rows) ----
  {
    const int er = wr + (lane >> 1);
    const int q4 = (lane & 1) * 4;
    const int t = s_tgt[er];
    const int w8 = 8 - tsn[t];
    const float invw = 1.f / (float)w8;
    float4v o;
    #pragma unroll
    for (int ci = 0; ci < 4; ci++){
      const int c = q4 + ci;
      float pe = 0.f;
      const int hi = (c + w8 < 8) ? (c + w8) : 8;
      for (int j = c; j < hi; j++) pe += sef[er * 8 + j];
      o[ci] = pe * invw;
    }
    *(float4v*)(pe8 + (size_t)(e0 + er) * 8 + q4) = o;
  }
}

// ---------------- coord aggregation (CSR gather) ----------------
__global__ __launch_bounds__(256) void k_agg(
    const u32* __restrict__ row_start, const float* __restrict__ pe8,
    const u32* __restrict__ st_s, const float* __restrict__ pooled,
    const float* __restrict__ coords, const float* __restrict__ w_r,
    float* __restrict__ out_coord)
{
  const int lane = threadIdx.x & 63;
  const int wv = threadIdx.x >> 6;
  const int n = blockIdx.x * 4 + wv;
  if (n >= NN) return;
  const u32 r0 = row_start[n], r1 = row_start[n + 1];
  const int cA = lane / 3, dA = lane - cA * 3;
  float sp = 0.f, sqd = 0.f;
  for (u32 p = r0; p < r1; p++){
    if (lane < 8)  sp  += pe8[(size_t)p * 8 + lane];
    if (lane < 24) sqd += pooled[(size_t)(st_s[p] & 0xffffu) * 3 + dA] * pe8[(size_t)p * 8 + cA];
  }
  if (lane < 24){
    const float wr0 = w_r[0];
    const float spc = __shfl(sp, cA);
    const float cv = coords[(size_t)n * 24 + lane];
    const u32 deg = r1 - r0;
    const float dv = (float)(deg > 0u ? deg : 1u);
    out_coord[(size_t)n * 24 + lane] = cv + wr0 * (cv * spc - sqd) / dv;
  }
}

// ---------------- final: het GEMM + BN + silu + residual (in-place on out_node) ----------------
__global__ __launch_bounds__(256) void k_final(
    const float* __restrict__ h, const u16* __restrict__ HtT,
    const float* __restrict__ het_b, const float* __restrict__ bn_g,
    const float* __restrict__ bn_b, float* __restrict__ out_node)
{
  __shared__ u16 sa[64 * MST];
  const int tid = threadIdx.x, lane = tid & 63, wv = tid >> 6, wrow = wv * 16;
  const int nb0 = blockIdx.x * 64;
  const int lc = lane & 15, lk = (lane >> 4) * 8;
  const f32x4 zero = {0.f, 0.f, 0.f, 0.f};

  #pragma unroll
  for (int jj = 0; jj < 8; jj++){
    const int idx = jj * 64 + lane;
    const int r = wrow + (idx >> 5);
    const int c4 = (idx & 31) * 4;
    int rn = nb0 + r; if (rn >= NN) rn = NN - 1;
    float4v v = *(const float4v*)(out_node + (size_t)rn * D + c4);
    ushort4v o = { f2b(v[0]), f2b(v[1]), f2b(v[2]), f2b(v[3]) };
    *(ushort4v*)(sa + r * MST + c4) = o;
  }

  f32x4 acc[8];
  #pragma unroll
  for (int nb = 0; nb < 8; nb++) acc[nb] = zero;
  #pragma unroll
  for (int kb = 0; kb < 4; kb++){
    short8 a = *(const short8*)(sa + (wrow + lc) * MST + kb * 32 + lk);
    #pragma unroll
    for (int nb = 0; nb < 8; nb++){
      short8 b = *(const short8*)(HtT + (size_t)(nb * 16 + lc) * D + kb * 32 + lk);
      acc[nb] = __builtin_amdgcn_mfma_f32_16x16x32_bf16(a, b, acc[nb], 0, 0, 0);
    }
  }
  const float invs = rsqrtf(1.f + 1e-5f);
  #pragma unroll
  for (int nb = 0; nb < 8; nb++){
    const int col = nb * 16 + lc;
    const float hb = het_b[col], g = bn_g[col], be = bn_b[col];
    #pragma unroll
    for (int j = 0; j < 4; j++){
      const int row = wrow + (lane >> 4) * 4 + j;
      const int node = nb0 + row;
      if (node < NN){
        float v = silu_f((acc[nb][j] + hb) * invs * g + be);
        out_node[(size_t)node * D + col] = v + h[(size_t)node * D + col];
      }
    }
  }
}

extern "C" void kernel_launch(void* const* d_in, const int* in_sizes, int n_in,
                              void* d_out, int out_size, void* d_ws, size_t ws_size,
                              hipStream_t stream)
{
  const float* h      = (const float*)d_in[0];
  const float* coords = (const float*)d_in[1];
  const float* cattr  = (const float*)d_in[2];
  const float* cw     = (const float*)d_in[3];
  const float* ewg    = (const float*)d_in[4];
  const int*   el     = (const int*)  d_in[5];
  const float* rl_w   = (const float*)d_in[6];
  const float* rl_b   = (const float*)d_in[7];
  const float* m_w1   = (const float*)d_in[8];
  const float* m_b1   = (const float*)d_in[9];
  const float* m_w2   = (const float*)d_in[10];
  const float* m_b2   = (const float*)d_in[11];
  const float* c_w1   = (const float*)d_in[12];
  const float* c_b1   = (const float*)d_in[13];
  const float* c_w2   = (const float*)d_in[14];
  const float* het_w  = (const float*)d_in[15];
  const float* het_b  = (const float*)d_in[16];
  const float* bn_g   = (const float*)d_in[17];
  const float* bn_b   = (const float*)d_in[18];
  const float* w_r    = (const float*)d_in[19];

  char* wsb = (char*)d_ws;
  size_t off = 0;
  auto take = [&](size_t bytes)->char*{
    char* p = wsb + off;
    off = (off + bytes + 255) & ~(size_t)255;
    return p;
  };
  u32*   maxsq  = (u32*)  take(4);
  float* pooled = (float*)take((size_t)NN * 3 * 4);
  int*   tsn    = (int*)  take((size_t)NN * 4);
  u32*   cnt    = (u32*)  take((size_t)NN * 4);
  u16*   hbf    = (u16*)  take((size_t)NN * D * 2);
  u16*   W12t   = (u16*)  take((size_t)256 * D * 2);
  u16*   W1cT   = (u16*)  take((size_t)D * 32 * 2);
  u16*   W2t    = (u16*)  take((size_t)D * D * 2);
  u16*   C1t    = (u16*)  take((size_t)D * D * 2);
  u16*   HtT    = (u16*)  take((size_t)D * D * 2);
  u16*   C2t    = (u16*)  take((size_t)16 * D * 2);
  u32*   row_start = (u32*)  take((size_t)(NN + 1) * 4);
  u32*   fill_ptr  = (u32*)  take((size_t)NN * 4);
  int*   eidx      = (int*)  take((size_t)NE * 4);
  u32*   st_s      = (u32*)  take((size_t)NE * 4);
  float* ew_s      = (float*)take((size_t)NE * 4);
  u16*   rad8b     = (u16*)  take((size_t)NE * 8 * 2);
  float* pe8       = (float*)take((size_t)NE * 8 * 4);
  float* hW12      = (float*)take((size_t)NN * 256 * 4);
  (void)ws_size;

  float* out_node  = (float*)d_out;
  float* out_coord = out_node + (size_t)NN * D;

  (void)hipMemsetAsync(maxsq, 0, 4, stream);
  (void)hipMemsetAsync(cnt, 0, (size_t)NN * 4, stream);
  (void)hipMemsetAsync(out_node, 0, (size_t)NN * D * 4, stream);

  k_prep_h  <<<dim3((NN * D / 4 + 255) / 256), dim3(256), 0, stream>>>(h, hbf);
  k_prep_w  <<<dim3((256*128 + 128*32 + 3*D*D + 16*D + 255) / 256), dim3(256), 0, stream>>>(
        m_w1, m_b1, m_w2, c_w1, c_w2, het_w, W12t, W1cT, W2t, C1t, HtT, C2t);
  k_node_pre<<<dim3((NN + 255) / 256), dim3(256), 0, stream>>>(coords, cw, pooled, tsn);
  k_edge_max<<<dim3((NE + 255) / 256), dim3(256), 0, stream>>>(coords, el, maxsq, cnt);
  k_scan    <<<dim3(1), dim3(1024), 0, stream>>>(cnt, row_start, fill_ptr);
  k_fill    <<<dim3((NE + 255) / 256), dim3(256), 0, stream>>>(el, fill_ptr, eidx);
  k_radial  <<<dim3(NE / 64), dim3(256), 0, stream>>>(
        coords, cattr, cw, el, eidx, ewg, rl_w, rl_b, maxsq, rad8b, st_s, ew_s);
  k_hw12    <<<dim3((NN + 63) / 64), dim3(256), 0, stream>>>(hbf, W12t, hW12);
  k_edge_mlp<<<dim3(NE / 128), dim3(256), 0, stream>>>(
        rad8b, st_s, ew_s, hW12, W1cT, W2t, C1t, C2t, m_b2, c_b1, tsn, out_node, pe8);
  k_agg     <<<dim3((NN + 3) / 4), dim3(256), 0, stream>>>(
        row_start, pe8, st_s, pooled, coords, w_r, out_coord);
  k_final   <<<dim3((NN + 63) / 64), dim3(256), 0, stream>>>(
        h, HtT, het_b, bn_g, bn_b, out_node);
}

// Round 8
// 727.374 us; speedup vs baseline: 1.2816x; 1.0778x over previous
//
#include <hip/hip_runtime.h>

#define NN 50000
#define NE 400000
#define D 128
#define MST 136
#define EPSV 1e-3f

typedef unsigned short u16;
typedef unsigned int u32;
typedef __attribute__((ext_vector_type(4))) float f32x4;
typedef __attribute__((ext_vector_type(4))) float float4v;
typedef __attribute__((ext_vector_type(8))) short short8;
typedef __attribute__((ext_vector_type(8))) unsigned short ushort8;
typedef __attribute__((ext_vector_type(4))) unsigned short ushort4v;

__device__ __forceinline__ u16 f2b(float f){
  u32 u = __float_as_uint(f);
  u32 r = u + 0x7fffu + ((u >> 16) & 1u);
  return (u16)(r >> 16);
}
__device__ __forceinline__ float b2f(u16 s){ return __uint_as_float(((u32)s) << 16); }
__device__ __forceinline__ float silu_f(float x){
  return x * __builtin_amdgcn_rcpf(1.f + __expf(-x));
}
__device__ __forceinline__ void atomAddF(float* p, float v){ unsafeAtomicAdd(p, v); }

// ================= K0: prep_h | prep_w | node_pre | edge_max =================
#define PH_B 6250
#define PW_B 344
#define NP_B 196
#define EM_B 1563
__global__ __launch_bounds__(256) void K0_prep(
    const float* __restrict__ h, const float* __restrict__ coords,
    const float* __restrict__ cw, const int* __restrict__ el,
    const float* __restrict__ m_w1, const float* __restrict__ m_b1,
    const float* __restrict__ m_w2, const float* __restrict__ c_w1,
    const float* __restrict__ c_w2, const float* __restrict__ het_w,
    u16* __restrict__ hbf, u16* __restrict__ W12t, u16* __restrict__ W1cT,
    u16* __restrict__ W2t, u16* __restrict__ C1t, u16* __restrict__ HtT,
    u16* __restrict__ C2t, float* __restrict__ pooled, int* __restrict__ tsn,
    u32* __restrict__ maxsq, u32* __restrict__ cnt)
{
  __shared__ float red[256];
  int bid = blockIdx.x;
  const int tid = threadIdx.x;

  if (bid < PH_B){
    int i = (bid * 256 + tid) * 4;
    if (i < NN * D){
      float4v v = *(const float4v*)(h + i);
      ushort4v o = { f2b(v[0]), f2b(v[1]), f2b(v[2]), f2b(v[3]) };
      *(ushort4v*)(hbf + i) = o;
    }
    return;
  }
  bid -= PH_B;
  if (bid < PW_B){
    int i = bid * 256 + tid;
    if (i < 256 * 128){
      int c = i >> 7, k = i & 127;
      W12t[i] = f2b(c < 128 ? m_w1[k * D + c] : m_w1[(128 + k) * D + (c - 128)]);
      return;
    }
    i -= 256 * 128;
    if (i < 128 * 32){
      int c = i >> 5, j = i & 31;
      W1cT[i] = (j < 8) ? f2b(m_w1[(256 + j) * D + c]) : (j == 8 ? f2b(m_b1[c]) : (u16)0);
      return;
    }
    i -= 128 * 32;
    if (i < D * D){ int c = i >> 7, k = i & 127; W2t[i] = f2b(m_w2[k * D + c]); return; }
    i -= D * D;
    if (i < D * D){ int c = i >> 7, k = i & 127; C1t[i] = f2b(c_w1[k * D + c]); return; }
    i -= D * D;
    if (i < D * D){ int c = i >> 7, k = i & 127; HtT[i] = f2b(het_w[k * D + c]); return; }
    i -= D * D;
    if (i < 16 * D){ int n = i >> 7, k = i & 127; C2t[i] = f2b(n < 8 ? c_w2[k * 8 + n] : 0.f); }
    return;
  }
  bid -= PW_B;
  if (bid < NP_B){
    int n = bid * 256 + tid;
    if (n >= NN) return;
    int cs = 0; float px = 0.f, py = 0.f, pz = 0.f;
    #pragma unroll
    for (int c = 0; c < 8; c++){
      float w = cw[n * 8 + c];
      if (w != 0.f){
        cs++;
        px += coords[(size_t)n * 24 + c * 3 + 0];
        py += coords[(size_t)n * 24 + c * 3 + 1];
        pz += coords[(size_t)n * 24 + c * 3 + 2];
      }
    }
    float inv = 1.f / ((float)cs + EPSV);
    pooled[n * 3 + 0] = px * inv;
    pooled[n * 3 + 1] = py * inv;
    pooled[n * 3 + 2] = pz * inv;
    int ts = cs - 1; ts = ts < 0 ? 0 : (ts > 7 ? 7 : ts);
    tsn[n] = ts;
    return;
  }
  bid -= NP_B;
  {
    int e = bid * 256 + tid;
    float vm = 0.f;
    if (e < NE){
      int s = el[e * 3 + 0], t = el[e * 3 + 1];
      float ct[24], cs_[24];
      const float4v* pt = (const float4v*)(coords + (size_t)t * 24);
      const float4v* ps = (const float4v*)(coords + (size_t)s * 24);
      #pragma unroll
      for (int i = 0; i < 6; i++){
        float4v v = pt[i];
        ct[i*4] = v[0]; ct[i*4+1] = v[1]; ct[i*4+2] = v[2]; ct[i*4+3] = v[3];
      }
      #pragma unroll
      for (int i = 0; i < 6; i++){
        float4v v = ps[i];
        cs_[i*4] = v[0]; cs_[i*4+1] = v[1]; cs_[i*4+2] = v[2]; cs_[i*4+3] = v[3];
      }
      #pragma unroll
      for (int c1 = 0; c1 < 8; c1++){
        #pragma unroll
        for (int c2 = 0; c2 < 8; c2++){
          float dx = ct[c1*3+0] - cs_[c2*3+0];
          float dy = ct[c1*3+1] - cs_[c2*3+1];
          float dz = ct[c1*3+2] - cs_[c2*3+2];
          vm = fmaxf(vm, dx*dx + dy*dy + dz*dz);
        }
      }
      atomicAdd(&cnt[t], 1u);
    }
    red[tid] = vm;
    __syncthreads();
    for (int s2 = 128; s2 > 0; s2 >>= 1){
      if (tid < s2) red[tid] = fmaxf(red[tid], red[tid + s2]);
      __syncthreads();
    }
    if (tid == 0) atomicMax(maxsq, __float_as_uint(red[0]));
  }
}

// ================= K1: CSR scan (single block) =================
__global__ __launch_bounds__(1024) void k_scan(const u32* __restrict__ cnt,
                                               u32* __restrict__ row_start,
                                               u32* __restrict__ fill_ptr){
  __shared__ u32 s[1024];
  const int tid = threadIdx.x;
  const int base = tid * 49;
  u32 tot = 0;
  #pragma unroll 1
  for (int k = 0; k < 49; k++){
    int i = base + k;
    if (i < NN) tot += cnt[i];
  }
  s[tid] = tot;
  __syncthreads();
  for (int off = 1; off < 1024; off <<= 1){
    u32 v = (tid >= off) ? s[tid - off] : 0u;
    __syncthreads();
    s[tid] += v;
    __syncthreads();
  }
  u32 running = s[tid] - tot;
  #pragma unroll 1
  for (int k = 0; k < 49; k++){
    int i = base + k;
    if (i <= NN){
      row_start[i] = running;
      if (i < NN){ fill_ptr[i] = running; running += cnt[i]; }
    }
  }
}

// ================= K2: CSR fill =================
__global__ __launch_bounds__(256) void k_fill(const int* __restrict__ el,
                                              u32* __restrict__ fill_ptr,
                                              int* __restrict__ eidx){
  int e = blockIdx.x * 256 + threadIdx.x;
  if (e >= NE) return;
  int t = el[e * 3 + 1];
  u32 pos = atomicAdd(&fill_ptr[t], 1u);
  eidx[pos] = e;
}

// ================= K3: radial (reg-resident, 2 thr/edge) | hw12 =================
#define RAD_B 3125
#define HW_B 782
__global__ __launch_bounds__(256) void K3_radial_hw12(
    const float* __restrict__ coords, const float* __restrict__ attr,
    const float* __restrict__ cw, const int* __restrict__ el,
    const int* __restrict__ eidx, const float* __restrict__ ewg,
    const float* __restrict__ rl_w, const float* __restrict__ rl_b,
    const u32* __restrict__ maxsq,
    const u16* __restrict__ hbf, const u16* __restrict__ W12t,
    u16* __restrict__ rad8b, u32* __restrict__ st_s, float* __restrict__ ew_s,
    u16* __restrict__ hW12b)
{
  __shared__ u16 sa[64 * MST];      // hw12 staging
  __shared__ float srl[64 * 8 + 8]; // radial: rl_w + rl_b
  const int tid = threadIdx.x;
  int bid = blockIdx.x;

  if (bid < RAD_B){
    // ---- radial: 128 edges/block, 2 threads/edge, register-resident ----
    {
      float v = (tid < 512) ? rl_w[tid] : (tid < 520 ? rl_b[tid - 512] : 0.f);
      if (tid < 520) srl[tid] = v;
    }
    __syncthreads();

    const int lane = tid & 63;
    const int wv = tid >> 6;
    const int eh = lane >> 1;          // edge within wave
    const int q = lane & 1;            // c-half: q*4 .. q*4+3
    const int p = bid * 128 + wv * 32 + eh;
    const int e = eidx[p];
    const int s = el[e * 3 + 0];
    const int t = el[e * 3 + 1];
    if (q == 0){
      st_s[p] = ((u32)t << 16) | (u32)s;
      ew_s[p] = ewg[e];
    }

    // loads: ct half (12), cs full (24), cwt half (4), cws full (8)
    float ct[12], cs_[24], cwt[4], cws[8];
    {
      const float* pt = coords + (size_t)t * 24 + q * 12;
      #pragma unroll
      for (int i = 0; i < 3; i++){
        float4v v = *(const float4v*)(pt + i * 4);
        ct[i*4] = v[0]; ct[i*4+1] = v[1]; ct[i*4+2] = v[2]; ct[i*4+3] = v[3];
      }
      const float* ps = coords + (size_t)s * 24;
      #pragma unroll
      for (int i = 0; i < 6; i++){
        float4v v = *(const float4v*)(ps + i * 4);
        cs_[i*4] = v[0]; cs_[i*4+1] = v[1]; cs_[i*4+2] = v[2]; cs_[i*4+3] = v[3];
      }
      float4v vt = *(const float4v*)(cw + (size_t)t * 8 + q * 4);
      cwt[0] = vt[0]; cwt[1] = vt[1]; cwt[2] = vt[2]; cwt[3] = vt[3];
      float4v v0 = *(const float4v*)(cw + (size_t)s * 8);
      float4v v1 = *(const float4v*)(cw + (size_t)s * 8 + 4);
      cws[0]=v0[0]; cws[1]=v0[1]; cws[2]=v0[2]; cws[3]=v0[3];
      cws[4]=v1[0]; cws[5]=v1[1]; cws[6]=v1[2]; cws[7]=v1[3];
    }
    const float scale = 1.f / (sqrtf(__uint_as_float(*maxsq)) + EPSV);

    // tmp[ci][b] over my 4 c's
    float tmp[4][8];
    #pragma unroll
    for (int ci = 0; ci < 4; ci++)
      #pragma unroll
      for (int b = 0; b < 8; b++) tmp[ci][b] = 0.f;
    #pragma unroll
    for (int d = 0; d < 8; d++){
      float asd[8];
      {
        const float* pa = attr + (size_t)s * 64 + d * 8;
        float4v a0 = *(const float4v*)(pa);
        float4v a1 = *(const float4v*)(pa + 4);
        asd[0]=a0[0]; asd[1]=a0[1]; asd[2]=a0[2]; asd[3]=a0[3];
        asd[4]=a1[0]; asd[5]=a1[1]; asd[6]=a1[2]; asd[7]=a1[3];
      }
      const float csd0 = cs_[d*3+0], csd1 = cs_[d*3+1], csd2 = cs_[d*3+2];
      const float cwsd = cws[d] * scale;
      #pragma unroll
      for (int ci = 0; ci < 4; ci++){
        float dx = ct[ci*3+0] - csd0;
        float dy = ct[ci*3+1] - csd1;
        float dz = ct[ci*3+2] - csd2;
        float msg = sqrtf(dx*dx + dy*dy + dz*dz) * cwsd * cwt[ci];
        #pragma unroll
        for (int b = 0; b < 8; b++) tmp[ci][b] += msg * asd[b];
      }
    }

    // rad[a][b] partial over my c's (full 8x8)
    float rad[8][8];
    #pragma unroll
    for (int a = 0; a < 8; a++)
      #pragma unroll
      for (int b = 0; b < 8; b++) rad[a][b] = 0.f;
    #pragma unroll
    for (int ci = 0; ci < 4; ci++){
      const int c = q * 4 + ci;
      float atc[8];
      const float* pa = attr + (size_t)t * 64 + c * 8;
      float4v a0 = *(const float4v*)(pa);
      float4v a1 = *(const float4v*)(pa + 4);
      atc[0]=a0[0]; atc[1]=a0[1]; atc[2]=a0[2]; atc[3]=a0[3];
      atc[4]=a1[0]; atc[5]=a1[1]; atc[6]=a1[2]; atc[7]=a1[3];
      #pragma unroll
      for (int a = 0; a < 8; a++)
        #pragma unroll
        for (int b = 0; b < 8; b++) rad[a][b] += atc[a] * tmp[ci][b];
    }
    // pair exchange -> full rad
    #pragma unroll
    for (int a = 0; a < 8; a++)
      #pragma unroll
      for (int b = 0; b < 8; b++) rad[a][b] += __shfl_xor(rad[a][b], 1);

    float sq = 0.f;
    #pragma unroll
    for (int a = 0; a < 8; a++)
      #pragma unroll
      for (int b = 0; b < 8; b++) sq += rad[a][b] * rad[a][b];
    const float rn = 1.f / (sqrtf(sq) + EPSV);

    // proj: my a-half
    float o[8];
    #pragma unroll
    for (int j = 0; j < 8; j++) o[j] = 0.f;
    #pragma unroll
    for (int ai = 0; ai < 4; ai++){
      const int a = q * 4 + ai;
      #pragma unroll
      for (int b = 0; b < 8; b++){
        const float v = rad[a][b] * rn;
        const int row = a * 8 + b;
        #pragma unroll
        for (int j = 0; j < 8; j++) o[j] += v * srl[row * 8 + j];
      }
    }
    #pragma unroll
    for (int j = 0; j < 8; j++) o[j] += __shfl_xor(o[j], 1);
    if (q == 0){
      ushort8 o8;
      #pragma unroll
      for (int j = 0; j < 8; j++) o8[j] = f2b(o[j] + srl[512 + j]);
      *(ushort8*)(rad8b + (size_t)p * 8) = o8;
    }
    return;
  }
  bid -= RAD_B;
  {
    // ---- hw12: hW12b = bf16( hbf @ [W1a|W1b] ) ----
    const int lane = tid & 63, wv = tid >> 6, wrow = wv * 16;
    const int nb0 = bid * 64;
    const int lc = lane & 15, lk = (lane >> 4) * 8;
    const f32x4 zero = {0.f, 0.f, 0.f, 0.f};

    #pragma unroll
    for (int jj = 0; jj < 4; jj++){
      const int flat = jj * 64 + lane;
      const int r = wrow + (flat >> 4);
      const int c8 = flat & 15;
      int rn2 = nb0 + r; if (rn2 >= NN) rn2 = NN - 1;
      *(ushort8*)(sa + r * MST + c8 * 8) = *(const ushort8*)(hbf + (size_t)rn2 * D + c8 * 8);
    }

    f32x4 acc[16];
    #pragma unroll
    for (int nb = 0; nb < 16; nb++) acc[nb] = zero;
    #pragma unroll
    for (int kb = 0; kb < 4; kb++){
      short8 a = *(const short8*)(sa + (wrow + lc) * MST + kb * 32 + lk);
      #pragma unroll
      for (int nb = 0; nb < 16; nb++){
        short8 b = *(const short8*)(W12t + (size_t)(nb * 16 + lc) * D + kb * 32 + lk);
        acc[nb] = __builtin_amdgcn_mfma_f32_16x16x32_bf16(a, b, acc[nb], 0, 0, 0);
      }
    }
    #pragma unroll
    for (int nb = 0; nb < 16; nb++){
      const int col = nb * 16 + lc;
      #pragma unroll
      for (int j = 0; j < 4; j++){
        const int row = wrow + (lane >> 4) * 4 + j;
        const int node = nb0 + row;
        if (node < NN) hW12b[(size_t)node * 256 + col] = f2b(acc[nb][j]);
      }
    }
  }
}

// ================= K4: fused edge MLP =================
__global__ __launch_bounds__(256, 4) void k_edge_mlp(
    const u16* __restrict__ rad8b, const u32* __restrict__ st_s,
    const float* __restrict__ ew_s, const u16* __restrict__ hW12b,
    const u16* __restrict__ W1cT, const u16* __restrict__ W2t,
    const u16* __restrict__ C1t, const u16* __restrict__ C2t,
    const float* __restrict__ m_b2, const float* __restrict__ c_b1,
    const int* __restrict__ tsn,
    float* __restrict__ out_node, float* __restrict__ pe8)
{
  __shared__ u16 sm[128 * MST];
  __shared__ float sef[128 * 8];
  __shared__ int s_tgt[128];
  __shared__ float s_ew[128];

  const int tid = threadIdx.x;
  const int lane = tid & 63;
  const int wv = tid >> 6;
  const int wr = wv * 32;
  const int e0 = blockIdx.x * 128;
  const int lc = lane & 15;
  const int khi = lane >> 4;
  const int lk = khi * 8;
  const f32x4 zero4 = {0.f, 0.f, 0.f, 0.f};
  const short8 zero8 = {0, 0, 0, 0, 0, 0, 0, 0};

  if (lane < 32){
    u32 v = st_s[e0 + wr + lane];
    s_tgt[wr + lane] = (int)(v >> 16);
    s_ew[wr + lane] = ew_s[e0 + wr + lane];
  }

  // ---- stage-sum: sm[r][c] = bf16( hW12b[t][c] + hW12b[s][128+c] ) ----
  {
    const int r = wr + (lane >> 1);
    const int ch = (lane & 1) * 64;
    u32 v = st_s[e0 + r];
    const int t = (int)(v >> 16), s = (int)(v & 0xffffu);
    const u16* pa = hW12b + (size_t)t * 256 + ch;
    const u16* pb = hW12b + (size_t)s * 256 + 128 + ch;
    #pragma unroll
    for (int i = 0; i < 8; i++){
      ushort8 va = *(const ushort8*)(pa + i * 8);
      ushort8 vb = *(const ushort8*)(pb + i * 8);
      ushort8 o;
      #pragma unroll
      for (int j = 0; j < 8; j++) o[j] = f2b(b2f((u16)va[j]) + b2f((u16)vb[j]));
      *(ushort8*)(sm + r * MST + ch + i * 8) = o;
    }
  }

  f32x4 acc0[8], acc1[8];

  // ---- rproj: rad8 @ W1c + 1*b1 ----
  {
    short8 ar0, ar1;
    if (khi == 0){
      ar0 = *(const short8*)(rad8b + (size_t)(e0 + wr + lc) * 8);
      ar1 = *(const short8*)(rad8b + (size_t)(e0 + wr + 16 + lc) * 8);
    } else if (khi == 1){
      ar0 = zero8; ar0[0] = (short)0x3F80;
      ar1 = ar0;
    } else {
      ar0 = zero8; ar1 = zero8;
    }
    #pragma unroll
    for (int nb = 0; nb < 8; nb++){
      short8 b = *(const short8*)(W1cT + (size_t)(nb * 16 + lc) * 32 + lk);
      acc0[nb] = __builtin_amdgcn_mfma_f32_16x16x32_bf16(ar0, b, zero4, 0, 0, 0);
      acc1[nb] = __builtin_amdgcn_mfma_f32_16x16x32_bf16(ar1, b, zero4, 0, 0, 0);
    }
  }
  #pragma unroll
  for (int nb = 0; nb < 8; nb++){
    const int col = nb * 16 + lc;
    #pragma unroll
    for (int j = 0; j < 4; j++){
      const int r0 = wr + khi * 4 + j;
      const int r1 = r0 + 16;
      float v0 = silu_f(acc0[nb][j] + b2f(sm[r0 * MST + col]));
      float v1 = silu_f(acc1[nb][j] + b2f(sm[r1 * MST + col]));
      sm[r0 * MST + col] = f2b(v0);
      sm[r1 * MST + col] = f2b(v1);
    }
  }

  // ---- GEMM2 ----
  #pragma unroll
  for (int nb = 0; nb < 8; nb++){ acc0[nb] = zero4; acc1[nb] = zero4; }
  #pragma unroll
  for (int kb = 0; kb < 4; kb++){
    short8 a0 = *(const short8*)(sm + (wr + lc) * MST + kb * 32 + lk);
    short8 a1 = *(const short8*)(sm + (wr + 16 + lc) * MST + kb * 32 + lk);
    #pragma unroll
    for (int nb = 0; nb < 8; nb++){
      short8 b = *(const short8*)(W2t + (size_t)(nb * 16 + lc) * D + kb * 32 + lk);
      acc0[nb] = __builtin_amdgcn_mfma_f32_16x16x32_bf16(a0, b, acc0[nb], 0, 0, 0);
      acc1[nb] = __builtin_amdgcn_mfma_f32_16x16x32_bf16(a1, b, acc1[nb], 0, 0, 0);
    }
  }
  #pragma unroll
  for (int nb = 0; nb < 8; nb++){
    const int col = nb * 16 + lc;
    const float bias = m_b2[col];
    #pragma unroll
    for (int j = 0; j < 4; j++){
      const int r0 = wr + khi * 4 + j;
      const int r1 = r0 + 16;
      sm[r0 * MST + col] = f2b(silu_f(acc0[nb][j] + bias));
      sm[r1 * MST + col] = f2b(silu_f(acc1[nb][j] + bias));
    }
  }

  // ---- segmented node_agg ----
  __syncthreads();
  {
    const int c = tid & 127;
    const int half = tid >> 7;
    const int rb = half * 64;
    float accv = 0.f;
    int curt = s_tgt[rb];
    #pragma unroll 1
    for (int r = rb; r < rb + 64; r++){
      int tt = s_tgt[r];
      if (tt != curt){
        atomAddF(&out_node[(size_t)curt * D + c], accv);
        accv = 0.f; curt = tt;
      }
      accv += b2f(sm[r * MST + c]) * s_ew[r];
    }
    atomAddF(&out_node[(size_t)curt * D + c], accv);
  }
  __syncthreads();

  // ---- GEMM3 ----
  #pragma unroll
  for (int nb = 0; nb < 8; nb++){ acc0[nb] = zero4; acc1[nb] = zero4; }
  #pragma unroll
  for (int kb = 0; kb < 4; kb++){
    short8 a0 = *(const short8*)(sm + (wr + lc) * MST + kb * 32 + lk);
    short8 a1 = *(const short8*)(sm + (wr + 16 + lc) * MST + kb * 32 + lk);
    #pragma unroll
    for (int nb = 0; nb < 8; nb++){
      short8 b = *(const short8*)(C1t + (size_t)(nb * 16 + lc) * D + kb * 32 + lk);
      acc0[nb] = __builtin_amdgcn_mfma_f32_16x16x32_bf16(a0, b, acc0[nb], 0, 0, 0);
      acc1[nb] = __builtin_amdgcn_mfma_f32_16x16x32_bf16(a1, b, acc1[nb], 0, 0, 0);
    }
  }
  #pragma unroll
  for (int nb = 0; nb < 8; nb++){
    const int col = nb * 16 + lc;
    const float bias = c_b1[col];
    #pragma unroll
    for (int j = 0; j < 4; j++){
      const int r0 = wr + khi * 4 + j;
      const int r1 = r0 + 16;
      sm[r0 * MST + col] = f2b(silu_f(acc0[nb][j] + bias));
      sm[r1 * MST + col] = f2b(silu_f(acc1[nb][j] + bias));
    }
  }

  // ---- GEMM4: ef = ef1 @ c_w2 ----
  {
    f32x4 e40 = zero4, e41 = zero4;
    #pragma unroll
    for (int kb = 0; kb < 4; kb++){
      short8 a0 = *(const short8*)(sm + (wr + lc) * MST + kb * 32 + lk);
      short8 a1 = *(const short8*)(sm + (wr + 16 + lc) * MST + kb * 32 + lk);
      short8 b = *(const short8*)(C2t + (size_t)lc * D + kb * 32 + lk);
      e40 = __builtin_amdgcn_mfma_f32_16x16x32_bf16(a0, b, e40, 0, 0, 0);
      e41 = __builtin_amdgcn_mfma_f32_16x16x32_bf16(a1, b, e41, 0, 0, 0);
    }
    if (lc < 8){
      #pragma unroll
      for (int j = 0; j < 4; j++){
        sef[(wr + khi * 4 + j) * 8 + lc] = e40[j];
        sef[(wr + 16 + khi * 4 + j) * 8 + lc] = e41[j];
      }
    }
  }

  // ---- pooled_edge windows -> pe8 ----
  {
    const int er = wr + (lane >> 1);
    const int q4 = (lane & 1) * 4;
    const int t = s_tgt[er];
    const int w8 = 8 - tsn[t];
    const float invw = 1.f / (float)w8;
    float4v o;
    #pragma unroll
    for (int ci = 0; ci < 4; ci++){
      const int c = q4 + ci;
      float pe = 0.f;
      const int hi = (c + w8 < 8) ? (c + w8) : 8;
      for (int j = c; j < hi; j++) pe += sef[er * 8 + j];
      o[ci] = pe * invw;
    }
    *(float4v*)(pe8 + (size_t)(e0 + er) * 8 + q4) = o;
  }
}

// ================= K5: agg | final =================
#define AGG_B 12500
#define FIN_B 782
__global__ __launch_bounds__(256) void K5_agg_final(
    const u32* __restrict__ row_start, const float* __restrict__ pe8,
    const u32* __restrict__ st_s, const float* __restrict__ pooled,
    const float* __restrict__ coords, const float* __restrict__ w_r,
    const float* __restrict__ h, const u16* __restrict__ HtT,
    const float* __restrict__ het_b, const float* __restrict__ bn_g,
    const float* __restrict__ bn_b,
    float* __restrict__ out_node, float* __restrict__ out_coord)
{
  __shared__ u16 sa[64 * MST];
  const int tid = threadIdx.x;
  int bid = blockIdx.x;

  if (bid < AGG_B){
    const int lane = tid & 63;
    const int wv = tid >> 6;
    const int n = bid * 4 + wv;
    if (n >= NN) return;
    const u32 r0 = row_start[n], r1 = row_start[n + 1];
    const int cA = lane / 3, dA = lane - cA * 3;
    float sp = 0.f, sqd = 0.f;
    for (u32 p = r0; p < r1; p++){
      if (lane < 8)  sp  += pe8[(size_t)p * 8 + lane];
      if (lane < 24) sqd += pooled[(size_t)(st_s[p] & 0xffffu) * 3 + dA] * pe8[(size_t)p * 8 + cA];
    }
    if (lane < 24){
      const float wr0 = w_r[0];
      const float spc = __shfl(sp, cA);
      const float cv = coords[(size_t)n * 24 + lane];
      const u32 deg = r1 - r0;
      const float dv = (float)(deg > 0u ? deg : 1u);
      out_coord[(size_t)n * 24 + lane] = cv + wr0 * (cv * spc - sqd) / dv;
    }
    return;
  }
  bid -= AGG_B;
  {
    const int lane = tid & 63, wv = tid >> 6, wrow = wv * 16;
    const int nb0 = bid * 64;
    const int lc = lane & 15, lk = (lane >> 4) * 8;
    const f32x4 zero = {0.f, 0.f, 0.f, 0.f};

    #pragma unroll
    for (int jj = 0; jj < 8; jj++){
      const int idx = jj * 64 + lane;
      const int r = wrow + (idx >> 5);
      const int c4 = (idx & 31) * 4;
      int rn = nb0 + r; if (rn >= NN) rn = NN - 1;
      float4v v = *(const float4v*)(out_node + (size_t)rn * D + c4);
      ushort4v o = { f2b(v[0]), f2b(v[1]), f2b(v[2]), f2b(v[3]) };
      *(ushort4v*)(sa + r * MST + c4) = o;
    }

    f32x4 acc[8];
    #pragma unroll
    for (int nb = 0; nb < 8; nb++) acc[nb] = zero;
    #pragma unroll
    for (int kb = 0; kb < 4; kb++){
      short8 a = *(const short8*)(sa + (wrow + lc) * MST + kb * 32 + lk);
      #pragma unroll
      for (int nb = 0; nb < 8; nb++){
        short8 b = *(const short8*)(HtT + (size_t)(nb * 16 + lc) * D + kb * 32 + lk);
        acc[nb] = __builtin_amdgcn_mfma_f32_16x16x32_bf16(a, b, acc[nb], 0, 0, 0);
      }
    }
    const float invs = rsqrtf(1.f + 1e-5f);
    #pragma unroll
    for (int nb = 0; nb < 8; nb++){
      const int col = nb * 16 + lc;
      const float hb = het_b[col], g = bn_g[col], be = bn_b[col];
      #pragma unroll
      for (int j = 0; j < 4; j++){
        const int row = wrow + (lane >> 4) * 4 + j;
        const int node = nb0 + row;
        if (node < NN){
          float v = silu_f((acc[nb][j] + hb) * invs * g + be);
          out_node[(size_t)node * D + col] = v + h[(size_t)node * D + col];
        }
      }
    }
  }
}

extern "C" void kernel_launch(void* const* d_in, const int* in_sizes, int n_in,
                              void* d_out, int out_size, void* d_ws, size_t ws_size,
                              hipStream_t stream)
{
  const float* h      = (const float*)d_in[0];
  const float* coords = (const float*)d_in[1];
  const float* cattr  = (const float*)d_in[2];
  const float* cw     = (const float*)d_in[3];
  const float* ewg    = (const float*)d_in[4];
  const int*   el     = (const int*)  d_in[5];
  const float* rl_w   = (const float*)d_in[6];
  const float* rl_b   = (const float*)d_in[7];
  const float* m_w1   = (const float*)d_in[8];
  const float* m_b1   = (const float*)d_in[9];
  const float* m_w2   = (const float*)d_in[10];
  const float* m_b2   = (const float*)d_in[11];
  const float* c_w1   = (const float*)d_in[12];
  const float* c_b1   = (const float*)d_in[13];
  const float* c_w2   = (const float*)d_in[14];
  const float* het_w  = (const float*)d_in[15];
  const float* het_b  = (const float*)d_in[16];
  const float* bn_g   = (const float*)d_in[17];
  const float* bn_b   = (const float*)d_in[18];
  const float* w_r    = (const float*)d_in[19];

  char* wsb = (char*)d_ws;
  size_t off = 0;
  auto take = [&](size_t bytes)->char*{
    char* p = wsb + off;
    off = (off + bytes + 255) & ~(size_t)255;
    return p;
  };
  u32*   cnt    = (u32*)  take((size_t)(NN + 1) * 4);   // cnt[NN] + maxsq
  u32*   maxsq  = cnt + NN;
  float* pooled = (float*)take((size_t)NN * 3 * 4);
  int*   tsn    = (int*)  take((size_t)NN * 4);
  u16*   hbf    = (u16*)  take((size_t)NN * D * 2);
  u16*   W12t   = (u16*)  take((size_t)256 * D * 2);
  u16*   W1cT   = (u16*)  take((size_t)D * 32 * 2);
  u16*   W2t    = (u16*)  take((size_t)D * D * 2);
  u16*   C1t    = (u16*)  take((size_t)D * D * 2);
  u16*   HtT    = (u16*)  take((size_t)D * D * 2);
  u16*   C2t    = (u16*)  take((size_t)16 * D * 2);
  u32*   row_start = (u32*)  take((size_t)(NN + 1) * 4);
  u32*   fill_ptr  = (u32*)  take((size_t)NN * 4);
  int*   eidx      = (int*)  take((size_t)NE * 4);
  u32*   st_s      = (u32*)  take((size_t)NE * 4);
  float* ew_s      = (float*)take((size_t)NE * 4);
  u16*   rad8b     = (u16*)  take((size_t)NE * 8 * 2);
  float* pe8       = (float*)take((size_t)NE * 8 * 4);
  u16*   hW12b     = (u16*)  take((size_t)NN * 256 * 2);
  (void)ws_size;

  float* out_node  = (float*)d_out;
  float* out_coord = out_node + (size_t)NN * D;

  (void)hipMemsetAsync(cnt, 0, (size_t)(NN + 1) * 4, stream);
  (void)hipMemsetAsync(out_node, 0, (size_t)NN * D * 4, stream);

  K0_prep<<<dim3(PH_B + PW_B + NP_B + EM_B), dim3(256), 0, stream>>>(
      h, coords, cw, el, m_w1, m_b1, m_w2, c_w1, c_w2, het_w,
      hbf, W12t, W1cT, W2t, C1t, HtT, C2t, pooled, tsn, maxsq, cnt);
  k_scan<<<dim3(1), dim3(1024), 0, stream>>>(cnt, row_start, fill_ptr);
  k_fill<<<dim3((NE + 255) / 256), dim3(256), 0, stream>>>(el, fill_ptr, eidx);
  K3_radial_hw12<<<dim3(RAD_B + HW_B), dim3(256), 0, stream>>>(
      coords, cattr, cw, el, eidx, ewg, rl_w, rl_b, maxsq,
      hbf, W12t, rad8b, st_s, ew_s, hW12b);
  k_edge_mlp<<<dim3(NE / 128), dim3(256), 0, stream>>>(
      rad8b, st_s, ew_s, hW12b, W1cT, W2t, C1t, C2t, m_b2, c_b1, tsn, out_node, pe8);
  K5_agg_final<<<dim3(AGG_B + FIN_B), dim3(256), 0, stream>>>(
      row_start, pe8, st_s, pooled, coords, w_r,
      h, HtT, het_b, bn_g, bn_b, out_node, out_coord);
}